// Round 1
// baseline (2476.806 us; speedup 1.0000x reference)
//
#include <hip/hip_runtime.h>
#include <math.h>

// ---------------------------------------------------------------------------
// GCN encoder forward:
//   deg/dinv -> BN stats -> [gemm1 -> agg] -> [gemm2(3 srcs) -> agg]
//   -> [gemm_mean, gemm_logstd -> agg x2]
// BN and ReLU are fused into GEMM staging; concat is never materialized.
// Workspace: dinv[N] | stats[512] | hbuf[N*128] | tmsbuf[N*128]  (~103 MB)
// d_out (N*128 floats total) is used as pre-aggregation scratch for conv1/2.
// ---------------------------------------------------------------------------

__global__ void zero_kernel(float* __restrict__ p, int n) {
    int i = blockIdx.x * blockDim.x + threadIdx.x;
    if (i < n) p[i] = 0.0f;
}

__global__ void count_deg(const int* __restrict__ ei, float* __restrict__ deg, int E) {
    int e = blockIdx.x * blockDim.x + threadIdx.x;
    if (e < E) atomicAdd(&deg[ei[E + e]], 1.0f);   // dst row of edge_index
}

__global__ void dinv_kernel(float* __restrict__ deg, int n) {
    int i = blockIdx.x * blockDim.x + threadIdx.x;
    if (i < n) deg[i] = 1.0f / sqrtf(deg[i] + 1.0f);  // +1 self-loop; deg>=1 always
}

// one block per row-stride; 128 threads = 128 columns
__global__ void bn_stats(const float* __restrict__ x, float* __restrict__ colsum,
                         float* __restrict__ colsumsq, int n) {
    int c = threadIdx.x;
    float s = 0.0f, sq = 0.0f;
    for (int r = blockIdx.x; r < n; r += gridDim.x) {
        float v = x[(size_t)r * 128 + c];
        s += v;
        sq = fmaf(v, v, sq);
    }
    atomicAdd(&colsum[c], s);
    atomicAdd(&colsumsq[c], sq);
}

__global__ void bn_finalize(const float* __restrict__ colsum, const float* __restrict__ colsumsq,
                            const float* __restrict__ gamma, const float* __restrict__ beta,
                            float* __restrict__ scale, float* __restrict__ shift, float invN) {
    int c = threadIdx.x;
    float mu = colsum[c] * invN;
    float var = colsumsq[c] * invN - mu * mu;
    float sc = gamma[c] / sqrtf(var + 1e-5f);
    scale[c] = sc;
    shift[c] = beta[c] - mu * sc;
}

// out[i][f] = bias[f], vectorized float4
template <int D>
__global__ void init_rows(float* __restrict__ out, const float* __restrict__ bias, int n) {
    int i = blockIdx.x * blockDim.x + threadIdx.x;  // over n*D/4
    if (i >= n * (D / 4)) return;
    int c4 = (i % (D / 4)) * 4;
    float4 b = *reinterpret_cast<const float4*>(bias + c4);
    reinterpret_cast<float4*>(out)[i] = b;
}

// ---------------------------------------------------------------------------
// GEMM: out[M x NC] = sum_a srcA[a][M x 128] @ W[a*128 : a*128+128, 0:NC]
// Per-source fused BN (v*scale[c]+shift[c]) and ReLU applied at LDS staging.
// Block: 256 threads, 64-row tile. Each thread: R rows x 8 cols.
// ---------------------------------------------------------------------------
template <int NC, int NA>
__global__ __launch_bounds__(256) void gemm_multi(
    const float* __restrict__ A0, const float* __restrict__ A1, const float* __restrict__ A2,
    int bnMask, int reluMask,
    const float* __restrict__ bnscale, const float* __restrict__ bnshift,
    const float* __restrict__ W, float* __restrict__ out, int M)
{
    constexpr int CG = NC / 8;     // col-groups (threads covering NC cols, 8 each)
    constexpr int TY = 256 / CG;   // row-groups
    constexpr int R  = 64 / TY;    // rows per thread
    __shared__ float lds[64 * 132];  // A tile, pad 132 to dodge bank conflicts

    const int t = threadIdx.x;
    const int tx = t % CG, ty = t / CG;
    const int row0 = blockIdx.x * 64;

    float4 acc[R][2];
#pragma unroll
    for (int i = 0; i < R; i++) {
        acc[i][0] = make_float4(0.f, 0.f, 0.f, 0.f);
        acc[i][1] = make_float4(0.f, 0.f, 0.f, 0.f);
    }

    const float* srcs[3] = {A0, A1, A2};
#pragma unroll
    for (int a = 0; a < NA; a++) {
        const float* __restrict__ A = srcs[a];
        const bool dobn = (bnMask >> a) & 1;
        const bool dorelu = (reluMask >> a) & 1;

        // stage 64x128 tile of A into LDS (coalesced float4), fused bn/relu
#pragma unroll
        for (int i = 0; i < 8; i++) {
            int lin = (i << 8) + t;        // 0..2047 float4 slots
            int row = lin >> 5;            // /32 slots per row
            int c4 = (lin & 31) << 2;
            int grow = row0 + row;
            float4 v = make_float4(0.f, 0.f, 0.f, 0.f);
            if (grow < M) v = *reinterpret_cast<const float4*>(A + (size_t)grow * 128 + c4);
            if (dobn) {
                float4 sc = *reinterpret_cast<const float4*>(bnscale + c4);
                float4 sh = *reinterpret_cast<const float4*>(bnshift + c4);
                v.x = fmaf(v.x, sc.x, sh.x);
                v.y = fmaf(v.y, sc.y, sh.y);
                v.z = fmaf(v.z, sc.z, sh.z);
                v.w = fmaf(v.w, sc.w, sh.w);
            }
            if (dorelu) {
                v.x = fmaxf(v.x, 0.f); v.y = fmaxf(v.y, 0.f);
                v.z = fmaxf(v.z, 0.f); v.w = fmaxf(v.w, 0.f);
            }
            *reinterpret_cast<float4*>(&lds[row * 132 + c4]) = v;
        }
        __syncthreads();

        const float* __restrict__ Wk = W + a * (128 * NC) + 8 * tx;
#pragma unroll 2
        for (int k = 0; k < 128; k++) {
            float4 w0 = *reinterpret_cast<const float4*>(Wk + k * NC);
            float4 w1 = *reinterpret_cast<const float4*>(Wk + k * NC + 4);
#pragma unroll
            for (int i = 0; i < R; i++) {
                float av = lds[(ty + TY * i) * 132 + k];
                acc[i][0].x = fmaf(av, w0.x, acc[i][0].x);
                acc[i][0].y = fmaf(av, w0.y, acc[i][0].y);
                acc[i][0].z = fmaf(av, w0.z, acc[i][0].z);
                acc[i][0].w = fmaf(av, w0.w, acc[i][0].w);
                acc[i][1].x = fmaf(av, w1.x, acc[i][1].x);
                acc[i][1].y = fmaf(av, w1.y, acc[i][1].y);
                acc[i][1].z = fmaf(av, w1.z, acc[i][1].z);
                acc[i][1].w = fmaf(av, w1.w, acc[i][1].w);
            }
        }
        __syncthreads();
    }

#pragma unroll
    for (int i = 0; i < R; i++) {
        int grow = row0 + ty + TY * i;
        if (grow < M) {
            *reinterpret_cast<float4*>(out + (size_t)grow * NC + 8 * tx) = acc[i][0];
            *reinterpret_cast<float4*>(out + (size_t)grow * NC + 8 * tx + 4) = acc[i][1];
        }
    }
}

// ---------------------------------------------------------------------------
// Scatter-aggregate: out[dst] += h[src] * dinv[src]*dinv[dst] over E+N edges
// (last N "edges" are self-loops). One wave (64 lanes) per edge.
// ---------------------------------------------------------------------------
template <int D>
__global__ void scatter_agg(const float* __restrict__ h, const float* __restrict__ dinv,
                            const int* __restrict__ ei, float* __restrict__ out,
                            int E, int ET) {
    int e = blockIdx.x * 4 + (threadIdx.x >> 6);
    if (e >= ET) return;
    int lane = threadIdx.x & 63;
    int s, d;
    if (e < E) { s = ei[e]; d = ei[E + e]; }
    else       { s = e - E; d = s; }
    float nrm = dinv[s] * dinv[d];
    if (D == 128) {
        int f = lane * 2;
        float2 m = *reinterpret_cast<const float2*>(h + (size_t)s * 128 + f);
        atomicAdd(out + (size_t)d * 128 + f,     m.x * nrm);
        atomicAdd(out + (size_t)d * 128 + f + 1, m.y * nrm);
    } else {
        float m = h[(size_t)s * 64 + lane];
        atomicAdd(out + (size_t)d * 64 + lane, m * nrm);
    }
}

// ---------------------------------------------------------------------------

extern "C" void kernel_launch(void* const* d_in, const int* in_sizes, int n_in,
                              void* d_out, int out_size, void* d_ws, size_t ws_size,
                              hipStream_t stream) {
    const float* x     = (const float*)d_in[0];
    const float* noise = (const float*)d_in[1];
    const int*   ei    = (const int*)d_in[2];
    const float* gamma = (const float*)d_in[3];
    const float* beta  = (const float*)d_in[4];
    const float* W1    = (const float*)d_in[5];
    const float* b1    = (const float*)d_in[6];
    const float* W2    = (const float*)d_in[7];
    const float* b2    = (const float*)d_in[8];
    const float* Wm    = (const float*)d_in[9];
    const float* bm    = (const float*)d_in[10];
    const float* Ws    = (const float*)d_in[11];
    const float* bs    = (const float*)d_in[12];

    const int N  = in_sizes[0] / 128;
    const int E  = in_sizes[2] / 2;
    const int ET = E + N;

    float* ws      = (float*)d_ws;
    float* deg     = ws;               // [N]  becomes dinv in place
    float* stats   = ws + N;           // [512]: colsum, colsumsq, scale, shift
    float* colsum  = stats;
    float* colsumsq= stats + 128;
    float* scale   = stats + 256;
    float* shift   = stats + 384;
    float* hbuf    = ws + N + 512;               // [N*128] h1 then h2
    float* tmsbuf  = hbuf + (size_t)N * 128;     // [N*128] tm | ts

    float* dout = (float*)d_out;       // N*128 floats total; scratch for conv1/2
    float* zm = dout;                  // [N*64]
    float* zs = dout + (size_t)N * 64; // [N*64]

    const int gblocks = (N + 63) / 64;
    const int scblocks = (ET + 3) / 4;

    // degree + BN statistics
    zero_kernel<<<(N + 512 + 255) / 256, 256, 0, stream>>>(deg, N + 512);
    count_deg<<<(E + 255) / 256, 256, 0, stream>>>(ei, deg, E);
    bn_stats<<<512, 128, 0, stream>>>(x, colsum, colsumsq, N);
    bn_finalize<<<1, 128, 0, stream>>>(colsum, colsumsq, gamma, beta, scale, shift, 1.0f / (float)N);
    dinv_kernel<<<(N + 255) / 256, 256, 0, stream>>>(deg, N);

    // conv1: h = bn(x) @ W1 -> dout; h1 = agg(h) + b1 (relu deferred to staging)
    gemm_multi<128, 1><<<gblocks, 256, 0, stream>>>(x, nullptr, nullptr,
        0b1, 0b0, scale, shift, W1, dout, N);
    init_rows<128><<<(N * 32 + 255) / 256, 256, 0, stream>>>(hbuf, b1, N);
    scatter_agg<128><<<scblocks, 256, 0, stream>>>(dout, deg, ei, hbuf, E, ET);

    // conv2: h = [bn(x), noise, relu(h1)] @ W2 -> dout; h2 = agg(h) + b2
    gemm_multi<128, 3><<<gblocks, 256, 0, stream>>>(x, noise, hbuf,
        0b001, 0b100, scale, shift, W2, dout, N);
    init_rows<128><<<(N * 32 + 255) / 256, 256, 0, stream>>>(hbuf, b2, N);
    scatter_agg<128><<<scblocks, 256, 0, stream>>>(dout, deg, ei, hbuf, E, ET);

    // mean / logstd: t = [bn(x), relu(h2)] @ W -> tmsbuf; z = agg(t) + b
    gemm_multi<64, 2><<<gblocks, 256, 0, stream>>>(x, hbuf, nullptr,
        0b01, 0b10, scale, shift, Wm, tmsbuf, N);
    gemm_multi<64, 2><<<gblocks, 256, 0, stream>>>(x, hbuf, nullptr,
        0b01, 0b10, scale, shift, Ws, tmsbuf + (size_t)N * 64, N);

    init_rows<64><<<(N * 16 + 255) / 256, 256, 0, stream>>>(zm, bm, N);
    init_rows<64><<<(N * 16 + 255) / 256, 256, 0, stream>>>(zs, bs, N);
    scatter_agg<64><<<scblocks, 256, 0, stream>>>(tmsbuf, deg, ei, zm, E, ET);
    scatter_agg<64><<<scblocks, 256, 0, stream>>>(tmsbuf + (size_t)N * 64, deg, ei, zs, E, ET);
}

// Round 2
// 825.328 us; speedup vs baseline: 3.0010x; 3.0010x over previous
//
#include <hip/hip_runtime.h>
#include <math.h>

// ---------------------------------------------------------------------------
// GCN encoder forward, CSR-gather formulation:
//   cnt=hist(dst) -> scan -> row_ptr -> fill edge_src (bucket sort)
//   hs = (srcs @ W) * dinv[row]            (GEMM epilogue scale)
//   out[d] = act(dinv[d]*(sum_{e in(d)} hs[src_e] + hs[d]) + bias)   (gather)
// BN/ReLU fused into GEMM staging / gather epilogue; concat never built.
// Final two convs share one GEMM via column-concatenated [Wm|Ws].
// ---------------------------------------------------------------------------

__global__ void zero_i32(int* __restrict__ p, int n) {
    int i = blockIdx.x * blockDim.x + threadIdx.x;
    if (i < n) p[i] = 0;
}

__global__ void count_deg(const int* __restrict__ ei, int* __restrict__ cnt, int E) {
    int e = blockIdx.x * blockDim.x + threadIdx.x;
    if (e < E) atomicAdd(&cnt[ei[E + e]], 1);
}

__global__ void dinv_from_cnt(const int* __restrict__ cnt, float* __restrict__ dinv, int n) {
    int i = blockIdx.x * blockDim.x + threadIdx.x;
    if (i < n) dinv[i] = rsqrtf((float)cnt[i] + 1.0f);   // +1 self-loop
}

// ---- exclusive scan of cnt -> row_ptr (1024 elems/block) -------------------
#define SCAN_BLK 256
#define SCAN_ELEMS 1024

__global__ void scan_blocks(const int* __restrict__ cnt, int* __restrict__ out,
                            int* __restrict__ bsums, int n) {
    __shared__ int lds[SCAN_BLK];
    int base = blockIdx.x * SCAN_ELEMS;
    int t = threadIdx.x;
    int v[4];
    int s = 0;
#pragma unroll
    for (int j = 0; j < 4; j++) {
        int i = base + t * 4 + j;
        v[j] = s;
        s += (i < n) ? cnt[i] : 0;
    }
    lds[t] = s;
    __syncthreads();
    for (int off = 1; off < SCAN_BLK; off <<= 1) {
        int val = (t >= off) ? lds[t - off] : 0;
        __syncthreads();
        lds[t] += val;
        __syncthreads();
    }
    int excl = (t == 0) ? 0 : lds[t - 1];
#pragma unroll
    for (int j = 0; j < 4; j++) {
        int i = base + t * 4 + j;
        if (i < n) out[i] = excl + v[j];
    }
    if (t == SCAN_BLK - 1) bsums[blockIdx.x] = lds[t];
}

__global__ void scan_bsums(int* __restrict__ bsums, int nb) {
    if (threadIdx.x == 0 && blockIdx.x == 0) {
        int acc = 0;
        for (int i = 0; i < nb; i++) { int c = bsums[i]; bsums[i] = acc; acc += c; }
    }
}

__global__ void scan_add(int* __restrict__ row_ptr, const int* __restrict__ bsums, int n, int E) {
    int i = blockIdx.x * blockDim.x + threadIdx.x;
    if (i < n) row_ptr[i] += bsums[i / SCAN_ELEMS];
    if (i == 0) row_ptr[n] = E;
}

// bucket-fill: consumes cnt (counts down to 0)
__global__ void fill_edges(const int* __restrict__ ei, const int* __restrict__ row_ptr,
                           int* __restrict__ cnt, int* __restrict__ edge_src, int E) {
    int e = blockIdx.x * blockDim.x + threadIdx.x;
    if (e >= E) return;
    int s = ei[e], d = ei[E + e];
    int off = atomicSub(&cnt[d], 1) - 1;
    edge_src[row_ptr[d] + off] = s;
}

// ---- BN statistics ---------------------------------------------------------
__global__ void bn_stats(const float* __restrict__ x, float* __restrict__ colsum,
                         float* __restrict__ colsumsq, int n) {
    int c = threadIdx.x;
    float s = 0.0f, sq = 0.0f;
    for (int r = blockIdx.x; r < n; r += gridDim.x) {
        float v = x[(size_t)r * 128 + c];
        s += v;
        sq = fmaf(v, v, sq);
    }
    atomicAdd(&colsum[c], s);
    atomicAdd(&colsumsq[c], sq);
}

__global__ void bn_finalize(const float* __restrict__ colsum, const float* __restrict__ colsumsq,
                            const float* __restrict__ gamma, const float* __restrict__ beta,
                            float* __restrict__ scale, float* __restrict__ shift, float invN) {
    int c = threadIdx.x;
    float mu = colsum[c] * invN;
    float var = colsumsq[c] * invN - mu * mu;
    float sc = gamma[c] / sqrtf(var + 1e-5f);
    scale[c] = sc;
    shift[c] = beta[c] - mu * sc;
}

// Wcat[k][0:64] = Wm[k][:], Wcat[k][64:128] = Ws[k][:]   (k in 0..255)
__global__ void build_wcat(const float* __restrict__ Wm, const float* __restrict__ Ws,
                           float* __restrict__ Wcat) {
    int i = blockIdx.x * blockDim.x + threadIdx.x;   // over 256*64
    if (i >= 256 * 64) return;
    int k = i >> 6, c = i & 63;
    Wcat[k * 128 + c] = Wm[i];
    Wcat[k * 128 + 64 + c] = Ws[i];
}

// ---------------------------------------------------------------------------
// GEMM: out[M x 128] = (sum_a srcA[a][M x 128] @ W[a*128:, :]) * rowscale[row]
// Per-source fused BN at LDS staging.
// ---------------------------------------------------------------------------
template <int NC, int NA>
__global__ __launch_bounds__(256) void gemm_multi(
    const float* __restrict__ A0, const float* __restrict__ A1, const float* __restrict__ A2,
    int bnMask,
    const float* __restrict__ bnscale, const float* __restrict__ bnshift,
    const float* __restrict__ W, const float* __restrict__ rowscale,
    float* __restrict__ out, int M)
{
    constexpr int CG = NC / 8;
    constexpr int TY = 256 / CG;
    constexpr int R  = 64 / TY;
    __shared__ float lds[64 * 132];

    const int t = threadIdx.x;
    const int tx = t % CG, ty = t / CG;
    const int row0 = blockIdx.x * 64;

    float4 acc[R][2];
#pragma unroll
    for (int i = 0; i < R; i++) {
        acc[i][0] = make_float4(0.f, 0.f, 0.f, 0.f);
        acc[i][1] = make_float4(0.f, 0.f, 0.f, 0.f);
    }

    const float* srcs[3] = {A0, A1, A2};
#pragma unroll
    for (int a = 0; a < NA; a++) {
        const float* __restrict__ A = srcs[a];
        const bool dobn = (bnMask >> a) & 1;

#pragma unroll
        for (int i = 0; i < 8; i++) {
            int lin = (i << 8) + t;
            int row = lin >> 5;
            int c4 = (lin & 31) << 2;
            int grow = row0 + row;
            float4 v = make_float4(0.f, 0.f, 0.f, 0.f);
            if (grow < M) v = *reinterpret_cast<const float4*>(A + (size_t)grow * 128 + c4);
            if (dobn) {
                float4 sc = *reinterpret_cast<const float4*>(bnscale + c4);
                float4 sh = *reinterpret_cast<const float4*>(bnshift + c4);
                v.x = fmaf(v.x, sc.x, sh.x);
                v.y = fmaf(v.y, sc.y, sh.y);
                v.z = fmaf(v.z, sc.z, sh.z);
                v.w = fmaf(v.w, sc.w, sh.w);
            }
            *reinterpret_cast<float4*>(&lds[row * 132 + c4]) = v;
        }
        __syncthreads();

        const float* __restrict__ Wk = W + a * (128 * NC) + 8 * tx;
#pragma unroll 2
        for (int k = 0; k < 128; k++) {
            float4 w0 = *reinterpret_cast<const float4*>(Wk + k * NC);
            float4 w1 = *reinterpret_cast<const float4*>(Wk + k * NC + 4);
#pragma unroll
            for (int i = 0; i < R; i++) {
                float av = lds[(ty + TY * i) * 132 + k];
                acc[i][0].x = fmaf(av, w0.x, acc[i][0].x);
                acc[i][0].y = fmaf(av, w0.y, acc[i][0].y);
                acc[i][0].z = fmaf(av, w0.z, acc[i][0].z);
                acc[i][0].w = fmaf(av, w0.w, acc[i][0].w);
                acc[i][1].x = fmaf(av, w1.x, acc[i][1].x);
                acc[i][1].y = fmaf(av, w1.y, acc[i][1].y);
                acc[i][1].z = fmaf(av, w1.z, acc[i][1].z);
                acc[i][1].w = fmaf(av, w1.w, acc[i][1].w);
            }
        }
        __syncthreads();
    }

#pragma unroll
    for (int i = 0; i < R; i++) {
        int grow = row0 + ty + TY * i;
        if (grow < M) {
            float dv = rowscale[grow];
            acc[i][0].x *= dv; acc[i][0].y *= dv; acc[i][0].z *= dv; acc[i][0].w *= dv;
            acc[i][1].x *= dv; acc[i][1].y *= dv; acc[i][1].z *= dv; acc[i][1].w *= dv;
            *reinterpret_cast<float4*>(out + (size_t)grow * NC + 8 * tx) = acc[i][0];
            *reinterpret_cast<float4*>(out + (size_t)grow * NC + 8 * tx + 4) = acc[i][1];
        }
    }
}

// ---------------------------------------------------------------------------
// Gather-aggregate (D=128): one wave per node.
// out[d] = act(dinv[d]*(sum hs[src] + hs[d]) + bias)
// ---------------------------------------------------------------------------
template <bool RELU>
__global__ void gather_agg(const float* __restrict__ hs, const float* __restrict__ dinv,
                           const int* __restrict__ row_ptr, const int* __restrict__ edge_src,
                           const float* __restrict__ bias, float* __restrict__ out, int n) {
    int node = blockIdx.x * 4 + (threadIdx.x >> 6);
    if (node >= n) return;
    int lane = threadIdx.x & 63;
    int beg = row_ptr[node], end = row_ptr[node + 1];
    const float2* hp = reinterpret_cast<const float2*>(hs);
    float2 acc = hp[(size_t)node * 64 + lane];         // self-loop term
    for (int e = beg; e < end; e++) {
        int s = edge_src[e];
        float2 m = hp[(size_t)s * 64 + lane];
        acc.x += m.x;
        acc.y += m.y;
    }
    float dv = dinv[node];
    float2 b = *reinterpret_cast<const float2*>(bias + lane * 2);
    float ox = fmaf(acc.x, dv, b.x);
    float oy = fmaf(acc.y, dv, b.y);
    if (RELU) { ox = fmaxf(ox, 0.f); oy = fmaxf(oy, 0.f); }
    float2* op = reinterpret_cast<float2*>(out);
    op[(size_t)node * 64 + lane] = make_float2(ox, oy);
}

// dual gather on interleaved t = [tm(64) | ts(64)] rows -> zm, zs
__global__ void gather_agg_dual(const float* __restrict__ hs, const float* __restrict__ dinv,
                                const int* __restrict__ row_ptr, const int* __restrict__ edge_src,
                                const float* __restrict__ bm, const float* __restrict__ bs,
                                float* __restrict__ zm, float* __restrict__ zs, int n) {
    int node = blockIdx.x * 4 + (threadIdx.x >> 6);
    if (node >= n) return;
    int lane = threadIdx.x & 63;
    int beg = row_ptr[node], end = row_ptr[node + 1];
    const float2* hp = reinterpret_cast<const float2*>(hs);
    float2 acc = hp[(size_t)node * 64 + lane];
    for (int e = beg; e < end; e++) {
        int s = edge_src[e];
        float2 m = hp[(size_t)s * 64 + lane];
        acc.x += m.x;
        acc.y += m.y;
    }
    float dv = dinv[node];
    if (lane < 32) {
        int c = lane * 2;  // column in zm
        float2 b = *reinterpret_cast<const float2*>(bm + c);
        reinterpret_cast<float2*>(zm)[(size_t)node * 32 + lane] =
            make_float2(fmaf(acc.x, dv, b.x), fmaf(acc.y, dv, b.y));
    } else {
        int c = lane * 2 - 64;  // column in zs
        float2 b = *reinterpret_cast<const float2*>(bs + c);
        reinterpret_cast<float2*>(zs)[(size_t)node * 32 + (lane - 32)] =
            make_float2(fmaf(acc.x, dv, b.x), fmaf(acc.y, dv, b.y));
    }
}

// ---------------------------------------------------------------------------

extern "C" void kernel_launch(void* const* d_in, const int* in_sizes, int n_in,
                              void* d_out, int out_size, void* d_ws, size_t ws_size,
                              hipStream_t stream) {
    const float* x     = (const float*)d_in[0];
    const float* noise = (const float*)d_in[1];
    const int*   ei    = (const int*)d_in[2];
    const float* gamma = (const float*)d_in[3];
    const float* beta  = (const float*)d_in[4];
    const float* W1    = (const float*)d_in[5];
    const float* b1    = (const float*)d_in[6];
    const float* W2    = (const float*)d_in[7];
    const float* b2    = (const float*)d_in[8];
    const float* Wm    = (const float*)d_in[9];
    const float* bm    = (const float*)d_in[10];
    const float* Ws    = (const float*)d_in[11];
    const float* bs    = (const float*)d_in[12];

    const int N  = in_sizes[0] / 128;
    const int E  = in_sizes[2] / 2;
    const int nb = (N + SCAN_ELEMS - 1) / SCAN_ELEMS;

    auto align256 = [](size_t b) { return (b + 255) & ~(size_t)255; };
    char* p = (char*)d_ws;
    int* cnt      = (int*)p;  p += align256((size_t)N * 4);
    int* row_ptr  = (int*)p;  p += align256((size_t)(N + 1) * 4);
    int* edge_src = (int*)p;  p += align256((size_t)E * 4);
    int* bsums    = (int*)p;  p += align256((size_t)nb * 4);
    float* dinv   = (float*)p; p += align256((size_t)N * 4);
    float* stats  = (float*)p; p += align256(512 * 4);
    float* wcat   = (float*)p; p += align256(256 * 128 * 4);
    float* hbuf   = (float*)p; p += align256((size_t)N * 128 * 4);

    float* colsum   = stats;
    float* colsumsq = stats + 128;
    float* scale    = stats + 256;
    float* shift    = stats + 384;

    float* dout = (float*)d_out;        // N*128 floats; P-scratch for conv1/2
    float* zm = dout;                   // [N*64]
    float* zs = dout + (size_t)N * 64;  // [N*64]

    const int gblocks = (N + 63) / 64;
    const int nblocks4 = (N + 3) / 4;

    // --- graph structure + BN stats ---
    zero_i32<<<(N + 255) / 256, 256, 0, stream>>>(cnt, N);
    zero_i32<<<2, 256, 0, stream>>>((int*)stats, 512);
    count_deg<<<(E + 255) / 256, 256, 0, stream>>>(ei, cnt, E);
    bn_stats<<<512, 128, 0, stream>>>(x, colsum, colsumsq, N);
    bn_finalize<<<1, 128, 0, stream>>>(colsum, colsumsq, gamma, beta, scale, shift, 1.0f / (float)N);
    scan_blocks<<<nb, SCAN_BLK, 0, stream>>>(cnt, row_ptr, bsums, N);
    scan_bsums<<<1, 64, 0, stream>>>(bsums, nb);
    scan_add<<<(N + 255) / 256, 256, 0, stream>>>(row_ptr, bsums, N, E);
    dinv_from_cnt<<<(N + 255) / 256, 256, 0, stream>>>(cnt, dinv, N);
    fill_edges<<<(E + 255) / 256, 256, 0, stream>>>(ei, row_ptr, cnt, edge_src, E);
    build_wcat<<<64, 256, 0, stream>>>(Wm, Ws, wcat);

    // conv1: hs = bn(x)@W1 * dinv -> dout;  h1 = relu(gather(hs)+b1) -> hbuf
    gemm_multi<128, 1><<<gblocks, 256, 0, stream>>>(x, nullptr, nullptr,
        0b1, scale, shift, W1, dinv, dout, N);
    gather_agg<true><<<nblocks4, 256, 0, stream>>>(dout, dinv, row_ptr, edge_src, b1, hbuf, N);

    // conv2: hs = [bn(x), noise, h1]@W2 * dinv -> dout;  h2 = relu(gather+b2) -> hbuf
    gemm_multi<128, 3><<<gblocks, 256, 0, stream>>>(x, noise, hbuf,
        0b001, scale, shift, W2, dinv, dout, N);
    gather_agg<true><<<nblocks4, 256, 0, stream>>>(dout, dinv, row_ptr, edge_src, b2, hbuf, N);

    // mean/logstd fused: t = [bn(x), h2]@[Wm|Ws] * dinv -> hbuf (in-place safe:
    // each block reads only its own 64-row hbuf tile before writing it)
    gemm_multi<128, 2><<<gblocks, 256, 0, stream>>>(x, hbuf, nullptr,
        0b01, scale, shift, wcat, dinv, hbuf, N);
    gather_agg_dual<<<nblocks4, 256, 0, stream>>>(hbuf, dinv, row_ptr, edge_src, bm, bs, zm, zs, N);
}

// Round 3
// 601.929 us; speedup vs baseline: 4.1148x; 1.3711x over previous
//
#include <hip/hip_runtime.h>
#include <math.h>

// ---------------------------------------------------------------------------
// GCN encoder forward, bf16 MFMA formulation:
//   CSR build (hist->scan->fill) ; BN stats (fp32)
//   xb16 = bn(x) in bf16 ; noise16 = bf16(noise) ; Wt = W^T in bf16
//   hs16 = (concat srcs @ W) * dinv[row]   (MFMA gemm, bf16 out)
//   out[d] = act(dinv[d]*(sum_in hs16[src] + hs16[d]) + bias)  (CSR gather)
// Intermediates bf16 (threshold is bf16-grade); stats/accum fp32.
// ---------------------------------------------------------------------------

typedef short bf16x8 __attribute__((ext_vector_type(8)));
typedef float f32x4 __attribute__((ext_vector_type(4)));

__device__ inline unsigned short f2bf(float f) {  // RNE
    unsigned int u = __builtin_bit_cast(unsigned int, f);
    u += 0x7fff + ((u >> 16) & 1);
    return (unsigned short)(u >> 16);
}
__device__ inline float bfl(unsigned int u) { return __builtin_bit_cast(float, u << 16); }
__device__ inline float bfh(unsigned int u) { return __builtin_bit_cast(float, u & 0xffff0000u); }

__global__ void zero_i32(int* __restrict__ p, int n) {
    int i = blockIdx.x * blockDim.x + threadIdx.x;
    if (i < n) p[i] = 0;
}

__global__ void count_deg(const int* __restrict__ ei, int* __restrict__ cnt, int E) {
    int e = blockIdx.x * blockDim.x + threadIdx.x;
    if (e < E) atomicAdd(&cnt[ei[E + e]], 1);
}

__global__ void dinv_from_cnt(const int* __restrict__ cnt, float* __restrict__ dinv, int n) {
    int i = blockIdx.x * blockDim.x + threadIdx.x;
    if (i < n) dinv[i] = rsqrtf((float)cnt[i] + 1.0f);   // +1 self-loop
}

#define SCAN_BLK 256
#define SCAN_ELEMS 1024

__global__ void scan_blocks(const int* __restrict__ cnt, int* __restrict__ out,
                            int* __restrict__ bsums, int n) {
    __shared__ int lds[SCAN_BLK];
    int base = blockIdx.x * SCAN_ELEMS;
    int t = threadIdx.x;
    int v[4];
    int s = 0;
#pragma unroll
    for (int j = 0; j < 4; j++) {
        int i = base + t * 4 + j;
        v[j] = s;
        s += (i < n) ? cnt[i] : 0;
    }
    lds[t] = s;
    __syncthreads();
    for (int off = 1; off < SCAN_BLK; off <<= 1) {
        int val = (t >= off) ? lds[t - off] : 0;
        __syncthreads();
        lds[t] += val;
        __syncthreads();
    }
    int excl = (t == 0) ? 0 : lds[t - 1];
#pragma unroll
    for (int j = 0; j < 4; j++) {
        int i = base + t * 4 + j;
        if (i < n) out[i] = excl + v[j];
    }
    if (t == SCAN_BLK - 1) bsums[blockIdx.x] = lds[t];
}

__global__ void scan_bsums(int* __restrict__ bsums, int nb) {
    if (threadIdx.x == 0 && blockIdx.x == 0) {
        int acc = 0;
        for (int i = 0; i < nb; i++) { int c = bsums[i]; bsums[i] = acc; acc += c; }
    }
}

__global__ void scan_add(int* __restrict__ row_ptr, const int* __restrict__ bsums, int n, int E) {
    int i = blockIdx.x * blockDim.x + threadIdx.x;
    if (i < n) row_ptr[i] += bsums[i / SCAN_ELEMS];
    if (i == 0) row_ptr[n] = E;
}

__global__ void fill_edges(const int* __restrict__ ei, const int* __restrict__ row_ptr,
                           int* __restrict__ cnt, int* __restrict__ edge_src, int E) {
    int e = blockIdx.x * blockDim.x + threadIdx.x;
    if (e >= E) return;
    int s = ei[e], d = ei[E + e];
    int off = atomicSub(&cnt[d], 1) - 1;
    edge_src[row_ptr[d] + off] = s;
}

__global__ void bn_stats(const float* __restrict__ x, float* __restrict__ colsum,
                         float* __restrict__ colsumsq, int n) {
    int c = threadIdx.x;
    float s = 0.0f, sq = 0.0f;
    for (int r = blockIdx.x; r < n; r += gridDim.x) {
        float v = x[(size_t)r * 128 + c];
        s += v;
        sq = fmaf(v, v, sq);
    }
    atomicAdd(&colsum[c], s);
    atomicAdd(&colsumsq[c], sq);
}

__global__ void bn_finalize(const float* __restrict__ colsum, const float* __restrict__ colsumsq,
                            const float* __restrict__ gamma, const float* __restrict__ beta,
                            float* __restrict__ scale, float* __restrict__ shift, float invN) {
    int c = threadIdx.x;
    float mu = colsum[c] * invN;
    float var = colsumsq[c] * invN - mu * mu;
    float sc = gamma[c] / sqrtf(var + 1e-5f);
    scale[c] = sc;
    shift[c] = beta[c] - mu * sc;
}

// x -> bn -> bf16 ; noise -> bf16. One pass, float4 in / ushort4 out.
__global__ void convert_inputs(const float4* __restrict__ x4, const float4* __restrict__ n4,
                               const float* __restrict__ scale, const float* __restrict__ shift,
                               ushort4* __restrict__ xb, ushort4* __restrict__ nb, int total4) {
    int i = blockIdx.x * blockDim.x + threadIdx.x;
    if (i >= total4) return;
    int c4 = (i & 31) << 2;
    float4 sc = *reinterpret_cast<const float4*>(scale + c4);
    float4 sh = *reinterpret_cast<const float4*>(shift + c4);
    float4 v = x4[i];
    ushort4 o;
    o.x = f2bf(fmaf(v.x, sc.x, sh.x));
    o.y = f2bf(fmaf(v.y, sc.y, sh.y));
    o.z = f2bf(fmaf(v.z, sc.z, sh.z));
    o.w = f2bf(fmaf(v.w, sc.w, sh.w));
    xb[i] = o;
    float4 w = n4[i];
    ushort4 p;
    p.x = f2bf(w.x); p.y = f2bf(w.y); p.z = f2bf(w.z); p.w = f2bf(w.w);
    nb[i] = p;
}

// Wt[c][k] = bf16(W[k][c]); Wt row stride = K
__global__ void transpose_w(const float* __restrict__ W, unsigned short* __restrict__ Wt,
                            int K, int C) {
    int i = blockIdx.x * blockDim.x + threadIdx.x;
    if (i >= K * C) return;
    int k = i / C, c = i % C;
    Wt[(size_t)c * K + k] = f2bf(W[i]);
}

// ---------------------------------------------------------------------------
// MFMA GEMM: hs[M x 128] = (sum_s A_s[M x 128] @ W[s*128:, :]) * dinv[row]
// 256 thr = 4 waves; wave = 32 rows x 128 cols. mfma(W_frag, A_frag) so the
// D fragment is column-packed: lane holds C[row_base+l15][n*16+4*lhi+r].
// ---------------------------------------------------------------------------
template <int NSRC>
__global__ __launch_bounds__(256) void gemm_mfma(
    const unsigned short* __restrict__ A0, const unsigned short* __restrict__ A1,
    const unsigned short* __restrict__ A2,
    const unsigned short* __restrict__ Wt,   // [128][NSRC*128]
    const float* __restrict__ dinv, unsigned short* __restrict__ out, int M)
{
    constexpr int KTOT = NSRC * 128;
    const int lane = threadIdx.x & 63;
    const int wid  = threadIdx.x >> 6;
    const int l15  = lane & 15, lhi = lane >> 4;
    const long r0 = (long)blockIdx.x * 128 + wid * 32 + l15;
    const long r1 = r0 + 16;
    const bool v0 = r0 < M, v1 = r1 < M;

    f32x4 acc[2][8];
#pragma unroll
    for (int g = 0; g < 2; g++)
#pragma unroll
        for (int n = 0; n < 8; n++)
            acc[g][n] = (f32x4){0.f, 0.f, 0.f, 0.f};

    const bf16x8 zero8 = (bf16x8){0,0,0,0,0,0,0,0};
    const unsigned short* __restrict__ srcs[3] = {A0, A1, A2};
#pragma unroll
    for (int s = 0; s < NSRC; s++) {
        const unsigned short* __restrict__ A = srcs[s];
        const unsigned short* a0p = A + r0 * 128 + lhi * 8;
        const unsigned short* a1p = A + r1 * 128 + lhi * 8;
#pragma unroll
        for (int kc = 0; kc < 4; kc++) {
            bf16x8 a0 = v0 ? *reinterpret_cast<const bf16x8*>(a0p + kc * 32) : zero8;
            bf16x8 a1 = v1 ? *reinterpret_cast<const bf16x8*>(a1p + kc * 32) : zero8;
            const unsigned short* wp = Wt + (size_t)l15 * KTOT + s * 128 + kc * 32 + lhi * 8;
#pragma unroll
            for (int n = 0; n < 8; n++) {
                bf16x8 w = *reinterpret_cast<const bf16x8*>(wp + (size_t)(n * 16) * KTOT);
                acc[0][n] = __builtin_amdgcn_mfma_f32_16x16x32_bf16(w, a0, acc[0][n], 0, 0, 0);
                acc[1][n] = __builtin_amdgcn_mfma_f32_16x16x32_bf16(w, a1, acc[1][n], 0, 0, 0);
            }
        }
    }

#pragma unroll
    for (int g = 0; g < 2; g++) {
        long row = g ? r1 : r0;
        if (row < M) {
            float dv = dinv[row];
            unsigned short* op = out + row * 128 + lhi * 4;
#pragma unroll
            for (int n = 0; n < 8; n++) {
                f32x4 v = acc[g][n];
                ushort4 pk;
                pk.x = f2bf(v[0] * dv);
                pk.y = f2bf(v[1] * dv);
                pk.z = f2bf(v[2] * dv);
                pk.w = f2bf(v[3] * dv);
                *reinterpret_cast<ushort4*>(op + n * 16) = pk;
            }
        }
    }
}

// ---------------------------------------------------------------------------
// CSR gather over bf16 rows: one wave per node, lane holds 2 cols (1 dword).
// ---------------------------------------------------------------------------
template <bool RELU>
__global__ void gather16(const unsigned int* __restrict__ hs, const float* __restrict__ dinv,
                         const int* __restrict__ row_ptr, const int* __restrict__ edge_src,
                         const float* __restrict__ bias, unsigned int* __restrict__ out, int n) {
    int node = blockIdx.x * 4 + (threadIdx.x >> 6);
    if (node >= n) return;
    int lane = threadIdx.x & 63;
    int beg = row_ptr[node], end = row_ptr[node + 1];
    unsigned int sv = hs[(size_t)node * 64 + lane];
    float ax = bfl(sv), ay = bfh(sv);
    for (int e = beg; e < end; e++) {
        int s = edge_src[e];
        unsigned int v = hs[(size_t)s * 64 + lane];
        ax += bfl(v); ay += bfh(v);
    }
    float dv = dinv[node];
    float2 b = *reinterpret_cast<const float2*>(bias + lane * 2);
    ax = fmaf(ax, dv, b.x);
    ay = fmaf(ay, dv, b.y);
    if (RELU) { ax = fmaxf(ax, 0.f); ay = fmaxf(ay, 0.f); }
    out[(size_t)node * 64 + lane] = ((unsigned int)f2bf(ay) << 16) | f2bf(ax);
}

// final: t rows = [tm(64) | ts(64)] bf16 -> zm, zs fp32
__global__ void gather_dual(const unsigned int* __restrict__ hs, const float* __restrict__ dinv,
                            const int* __restrict__ row_ptr, const int* __restrict__ edge_src,
                            const float* __restrict__ bm, const float* __restrict__ bs,
                            float2* __restrict__ zm, float2* __restrict__ zs, int n) {
    int node = blockIdx.x * 4 + (threadIdx.x >> 6);
    if (node >= n) return;
    int lane = threadIdx.x & 63;
    int beg = row_ptr[node], end = row_ptr[node + 1];
    unsigned int sv = hs[(size_t)node * 64 + lane];
    float ax = bfl(sv), ay = bfh(sv);
    for (int e = beg; e < end; e++) {
        int s = edge_src[e];
        unsigned int v = hs[(size_t)s * 64 + lane];
        ax += bfl(v); ay += bfh(v);
    }
    float dv = dinv[node];
    if (lane < 32) {
        float2 b = *reinterpret_cast<const float2*>(bm + lane * 2);
        zm[(size_t)node * 32 + lane] = make_float2(fmaf(ax, dv, b.x), fmaf(ay, dv, b.y));
    } else {
        int l = lane - 32;
        float2 b = *reinterpret_cast<const float2*>(bs + l * 2);
        zs[(size_t)node * 32 + l] = make_float2(fmaf(ax, dv, b.x), fmaf(ay, dv, b.y));
    }
}

// ---------------------------------------------------------------------------

extern "C" void kernel_launch(void* const* d_in, const int* in_sizes, int n_in,
                              void* d_out, int out_size, void* d_ws, size_t ws_size,
                              hipStream_t stream) {
    const float* x     = (const float*)d_in[0];
    const float* noise = (const float*)d_in[1];
    const int*   ei    = (const int*)d_in[2];
    const float* gamma = (const float*)d_in[3];
    const float* beta  = (const float*)d_in[4];
    const float* W1    = (const float*)d_in[5];
    const float* b1    = (const float*)d_in[6];
    const float* W2    = (const float*)d_in[7];
    const float* b2    = (const float*)d_in[8];
    const float* Wm    = (const float*)d_in[9];
    const float* bm    = (const float*)d_in[10];
    const float* Ws    = (const float*)d_in[11];
    const float* bs    = (const float*)d_in[12];

    const int N  = in_sizes[0] / 128;
    const int E  = in_sizes[2] / 2;
    const int nb = (N + SCAN_ELEMS - 1) / SCAN_ELEMS;

    auto align256 = [](size_t b) { return (b + 255) & ~(size_t)255; };
    char* p = (char*)d_ws;
    int* cnt      = (int*)p;  p += align256((size_t)N * 4);
    int* row_ptr  = (int*)p;  p += align256((size_t)(N + 1) * 4);
    int* edge_src = (int*)p;  p += align256((size_t)E * 4);
    int* bsums    = (int*)p;  p += align256((size_t)nb * 4);
    float* dinv   = (float*)p; p += align256((size_t)N * 4);
    float* stats  = (float*)p; p += align256(512 * 4);
    unsigned short* Wt1 = (unsigned short*)p; p += align256(128 * 128 * 2);
    unsigned short* Wt2 = (unsigned short*)p; p += align256(128 * 384 * 2);
    unsigned short* Wtc = (unsigned short*)p; p += align256(128 * 256 * 2);
    unsigned short* xb16 = (unsigned short*)p; p += align256((size_t)N * 128 * 2);
    unsigned short* n16  = (unsigned short*)p; p += align256((size_t)N * 128 * 2);  // noise, then hs3
    unsigned short* h16  = (unsigned short*)p; p += align256((size_t)N * 128 * 2);  // h1, then h2

    float* colsum   = stats;
    float* colsumsq = stats + 128;
    float* scale    = stats + 256;
    float* shift    = stats + 384;

    float* dout = (float*)d_out;                       // N*128 fp32
    unsigned short* hs12 = (unsigned short*)d_out;     // conv1/2 hs scratch (bf16, fits)
    unsigned short* hs3  = n16;                        // noise dead after conv2
    float2* zm = (float2*)dout;                        // [N*32] float2
    float2* zs = (float2*)(dout + (size_t)N * 64);

    const int gblocks = (N + 127) / 128;
    const int nblocks4 = (N + 3) / 4;

    // --- graph structure + BN stats + conversions ---
    zero_i32<<<(N + 255) / 256, 256, 0, stream>>>(cnt, N);
    zero_i32<<<2, 256, 0, stream>>>((int*)stats, 512);
    count_deg<<<(E + 255) / 256, 256, 0, stream>>>(ei, cnt, E);
    bn_stats<<<512, 128, 0, stream>>>(x, colsum, colsumsq, N);
    bn_finalize<<<1, 128, 0, stream>>>(colsum, colsumsq, gamma, beta, scale, shift, 1.0f / (float)N);
    scan_blocks<<<nb, SCAN_BLK, 0, stream>>>(cnt, row_ptr, bsums, N);
    scan_bsums<<<1, 64, 0, stream>>>(bsums, nb);
    scan_add<<<(N + 255) / 256, 256, 0, stream>>>(row_ptr, bsums, N, E);
    dinv_from_cnt<<<(N + 255) / 256, 256, 0, stream>>>(cnt, dinv, N);
    fill_edges<<<(E + 255) / 256, 256, 0, stream>>>(ei, row_ptr, cnt, edge_src, E);
    convert_inputs<<<(N * 32 + 255) / 256, 256, 0, stream>>>(
        (const float4*)x, (const float4*)noise, scale, shift,
        (ushort4*)xb16, (ushort4*)n16, N * 32);
    transpose_w<<<(128 * 128 + 255) / 256, 256, 0, stream>>>(W1, Wt1, 128, 128);
    transpose_w<<<(384 * 128 + 255) / 256, 256, 0, stream>>>(W2, Wt2, 384, 128);
    transpose_w<<<(256 * 64 + 255) / 256, 256, 0, stream>>>(Wm, Wtc, 256, 64);
    transpose_w<<<(256 * 64 + 255) / 256, 256, 0, stream>>>(Ws, Wtc + 64 * 256, 256, 64);

    // conv1
    gemm_mfma<1><<<gblocks, 256, 0, stream>>>(xb16, nullptr, nullptr, Wt1, dinv, hs12, N);
    gather16<true><<<nblocks4, 256, 0, stream>>>((const unsigned int*)hs12, dinv, row_ptr,
                                                 edge_src, b1, (unsigned int*)h16, N);
    // conv2
    gemm_mfma<3><<<gblocks, 256, 0, stream>>>(xb16, n16, h16, Wt2, dinv, hs12, N);
    gather16<true><<<nblocks4, 256, 0, stream>>>((const unsigned int*)hs12, dinv, row_ptr,
                                                 edge_src, b2, (unsigned int*)h16, N);
    // mean/logstd fused (hs -> n16 slot; d_out now gets final fp32 outputs)
    gemm_mfma<2><<<gblocks, 256, 0, stream>>>(xb16, h16, nullptr, Wtc, dinv, hs3, N);
    gather_dual<<<nblocks4, 256, 0, stream>>>((const unsigned int*)hs3, dinv, row_ptr,
                                              edge_src, bm, bs, zm, zs, N);
}

// Round 4
// 494.312 us; speedup vs baseline: 5.0106x; 1.2177x over previous
//
#include <hip/hip_runtime.h>
#include <math.h>

// ---------------------------------------------------------------------------
// GCN encoder forward, bf16 MFMA formulation:
//   CSR build (hist->scan->fill) ; BN stats (fp32, vectorized)
//   xb16 = bn(x) in bf16 ; noise16 = bf16(noise) ; Wt = W^T in bf16
//   hs16 = (concat srcs @ W) * dinv[row]   (MFMA gemm, bf16 out)
//   out[d] = act(dinv[d]*(sum_in hs16[src] + hs16[d]) + bias)  (CSR gather,
//            4-edge unrolled for memory-level parallelism)
// ---------------------------------------------------------------------------

typedef short bf16x8 __attribute__((ext_vector_type(8)));
typedef float f32x4 __attribute__((ext_vector_type(4)));

__device__ inline unsigned short f2bf(float f) {  // RNE
    unsigned int u = __builtin_bit_cast(unsigned int, f);
    u += 0x7fff + ((u >> 16) & 1);
    return (unsigned short)(u >> 16);
}
__device__ inline float bfl(unsigned int u) { return __builtin_bit_cast(float, u << 16); }
__device__ inline float bfh(unsigned int u) { return __builtin_bit_cast(float, u & 0xffff0000u); }

__global__ void zero_i32(int* __restrict__ p, int n) {
    int i = blockIdx.x * blockDim.x + threadIdx.x;
    if (i < n) p[i] = 0;
}

__global__ void count_deg(const int* __restrict__ ei, int* __restrict__ cnt, int E) {
    int e = blockIdx.x * blockDim.x + threadIdx.x;
    if (e < E) atomicAdd(&cnt[ei[E + e]], 1);
}

__global__ void dinv_from_cnt(const int* __restrict__ cnt, float* __restrict__ dinv, int n) {
    int i = blockIdx.x * blockDim.x + threadIdx.x;
    if (i < n) dinv[i] = rsqrtf((float)cnt[i] + 1.0f);   // +1 self-loop
}

#define SCAN_BLK 256
#define SCAN_ELEMS 1024

__global__ void scan_blocks(const int* __restrict__ cnt, int* __restrict__ out,
                            int* __restrict__ bsums, int n) {
    __shared__ int lds[SCAN_BLK];
    int base = blockIdx.x * SCAN_ELEMS;
    int t = threadIdx.x;
    int v[4];
    int s = 0;
#pragma unroll
    for (int j = 0; j < 4; j++) {
        int i = base + t * 4 + j;
        v[j] = s;
        s += (i < n) ? cnt[i] : 0;
    }
    lds[t] = s;
    __syncthreads();
    for (int off = 1; off < SCAN_BLK; off <<= 1) {
        int val = (t >= off) ? lds[t - off] : 0;
        __syncthreads();
        lds[t] += val;
        __syncthreads();
    }
    int excl = (t == 0) ? 0 : lds[t - 1];
#pragma unroll
    for (int j = 0; j < 4; j++) {
        int i = base + t * 4 + j;
        if (i < n) out[i] = excl + v[j];
    }
    if (t == SCAN_BLK - 1) bsums[blockIdx.x] = lds[t];
}

__global__ void scan_bsums(int* __restrict__ bsums, int nb) {
    if (threadIdx.x == 0 && blockIdx.x == 0) {
        int acc = 0;
        for (int i = 0; i < nb; i++) { int c = bsums[i]; bsums[i] = acc; acc += c; }
    }
}

__global__ void scan_add(int* __restrict__ row_ptr, const int* __restrict__ bsums, int n, int E) {
    int i = blockIdx.x * blockDim.x + threadIdx.x;
    if (i < n) row_ptr[i] += bsums[i / SCAN_ELEMS];
    if (i == 0) row_ptr[n] = E;
}

__global__ void fill_edges(const int* __restrict__ ei, const int* __restrict__ row_ptr,
                           int* __restrict__ cnt, int* __restrict__ edge_src, int E) {
    int e = blockIdx.x * blockDim.x + threadIdx.x;
    if (e >= E) return;
    int s = ei[e], d = ei[E + e];
    int off = atomicSub(&cnt[d], 1) - 1;
    edge_src[row_ptr[d] + off] = s;
}

// ---- BN statistics: 256 thr = 8 row-slices x 32 col-groups(float4) --------
__global__ __launch_bounds__(256) void bn_stats(const float4* __restrict__ x4,
                                                float* __restrict__ colsum,
                                                float* __restrict__ colsumsq, int n) {
    int t = threadIdx.x;
    int cg = t & 31;          // column group: cols cg*4 .. cg*4+3
    int rs = t >> 5;          // row slice 0..7
    float4 s = make_float4(0.f, 0.f, 0.f, 0.f);
    float4 q = make_float4(0.f, 0.f, 0.f, 0.f);
    const int stride = gridDim.x * 16;
    for (int r = blockIdx.x * 16 + rs * 2; r < n; r += stride) {
        float4 v = x4[(size_t)r * 32 + cg];
        s.x += v.x; s.y += v.y; s.z += v.z; s.w += v.w;
        q.x = fmaf(v.x, v.x, q.x); q.y = fmaf(v.y, v.y, q.y);
        q.z = fmaf(v.z, v.z, q.z); q.w = fmaf(v.w, v.w, q.w);
        int r2 = r + 1;
        if (r2 < n) {
            float4 w = x4[(size_t)r2 * 32 + cg];
            s.x += w.x; s.y += w.y; s.z += w.z; s.w += w.w;
            q.x = fmaf(w.x, w.x, q.x); q.y = fmaf(w.y, w.y, q.y);
            q.z = fmaf(w.z, w.z, q.z); q.w = fmaf(w.w, w.w, q.w);
        }
    }
    __shared__ float4 lds[2][8][32];
    lds[0][rs][cg] = s;
    lds[1][rs][cg] = q;
    __syncthreads();
    if (t < 64) {
        int which = t >> 5;       // 0: sum, 1: sumsq
        int c = t & 31;
        float4 a = lds[which][0][c];
#pragma unroll
        for (int i = 1; i < 8; i++) {
            float4 b = lds[which][i][c];
            a.x += b.x; a.y += b.y; a.z += b.z; a.w += b.w;
        }
        float* dst = which ? colsumsq : colsum;
        atomicAdd(&dst[c * 4 + 0], a.x);
        atomicAdd(&dst[c * 4 + 1], a.y);
        atomicAdd(&dst[c * 4 + 2], a.z);
        atomicAdd(&dst[c * 4 + 3], a.w);
    }
}

__global__ void bn_finalize(const float* __restrict__ colsum, const float* __restrict__ colsumsq,
                            const float* __restrict__ gamma, const float* __restrict__ beta,
                            float* __restrict__ scale, float* __restrict__ shift, float invN) {
    int c = threadIdx.x;
    float mu = colsum[c] * invN;
    float var = colsumsq[c] * invN - mu * mu;
    float sc = gamma[c] / sqrtf(var + 1e-5f);
    scale[c] = sc;
    shift[c] = beta[c] - mu * sc;
}

// x -> bn -> bf16 ; noise -> bf16. One pass, float4 in / ushort4 out.
__global__ void convert_inputs(const float4* __restrict__ x4, const float4* __restrict__ n4,
                               const float* __restrict__ scale, const float* __restrict__ shift,
                               ushort4* __restrict__ xb, ushort4* __restrict__ nb, int total4) {
    int i = blockIdx.x * blockDim.x + threadIdx.x;
    if (i >= total4) return;
    int c4 = (i & 31) << 2;
    float4 sc = *reinterpret_cast<const float4*>(scale + c4);
    float4 sh = *reinterpret_cast<const float4*>(shift + c4);
    float4 v = x4[i];
    ushort4 o;
    o.x = f2bf(fmaf(v.x, sc.x, sh.x));
    o.y = f2bf(fmaf(v.y, sc.y, sh.y));
    o.z = f2bf(fmaf(v.z, sc.z, sh.z));
    o.w = f2bf(fmaf(v.w, sc.w, sh.w));
    xb[i] = o;
    float4 w = n4[i];
    ushort4 p;
    p.x = f2bf(w.x); p.y = f2bf(w.y); p.z = f2bf(w.z); p.w = f2bf(w.w);
    nb[i] = p;
}

// Wt[c][k] = bf16(W[k][c]); Wt row stride = K
__global__ void transpose_w(const float* __restrict__ W, unsigned short* __restrict__ Wt,
                            int K, int C) {
    int i = blockIdx.x * blockDim.x + threadIdx.x;
    if (i >= K * C) return;
    int k = i / C, c = i % C;
    Wt[(size_t)c * K + k] = f2bf(W[i]);
}

// ---------------------------------------------------------------------------
// MFMA GEMM: hs[M x 128] = (sum_s A_s[M x 128] @ W[s*128:, :]) * dinv[row]
// ---------------------------------------------------------------------------
template <int NSRC>
__global__ __launch_bounds__(256) void gemm_mfma(
    const unsigned short* __restrict__ A0, const unsigned short* __restrict__ A1,
    const unsigned short* __restrict__ A2,
    const unsigned short* __restrict__ Wt,   // [128][NSRC*128]
    const float* __restrict__ dinv, unsigned short* __restrict__ out, int M)
{
    constexpr int KTOT = NSRC * 128;
    const int lane = threadIdx.x & 63;
    const int wid  = threadIdx.x >> 6;
    const int l15  = lane & 15, lhi = lane >> 4;
    const long r0 = (long)blockIdx.x * 128 + wid * 32 + l15;
    const long r1 = r0 + 16;
    const bool v0 = r0 < M, v1 = r1 < M;

    f32x4 acc[2][8];
#pragma unroll
    for (int g = 0; g < 2; g++)
#pragma unroll
        for (int n = 0; n < 8; n++)
            acc[g][n] = (f32x4){0.f, 0.f, 0.f, 0.f};

    const bf16x8 zero8 = (bf16x8){0,0,0,0,0,0,0,0};
    const unsigned short* __restrict__ srcs[3] = {A0, A1, A2};
#pragma unroll
    for (int s = 0; s < NSRC; s++) {
        const unsigned short* __restrict__ A = srcs[s];
        const unsigned short* a0p = A + r0 * 128 + lhi * 8;
        const unsigned short* a1p = A + r1 * 128 + lhi * 8;
#pragma unroll
        for (int kc = 0; kc < 4; kc++) {
            bf16x8 a0 = v0 ? *reinterpret_cast<const bf16x8*>(a0p + kc * 32) : zero8;
            bf16x8 a1 = v1 ? *reinterpret_cast<const bf16x8*>(a1p + kc * 32) : zero8;
            const unsigned short* wp = Wt + (size_t)l15 * KTOT + s * 128 + kc * 32 + lhi * 8;
#pragma unroll
            for (int n = 0; n < 8; n++) {
                bf16x8 w = *reinterpret_cast<const bf16x8*>(wp + (size_t)(n * 16) * KTOT);
                acc[0][n] = __builtin_amdgcn_mfma_f32_16x16x32_bf16(w, a0, acc[0][n], 0, 0, 0);
                acc[1][n] = __builtin_amdgcn_mfma_f32_16x16x32_bf16(w, a1, acc[1][n], 0, 0, 0);
            }
        }
    }

#pragma unroll
    for (int g = 0; g < 2; g++) {
        long row = g ? r1 : r0;
        if (row < M) {
            float dv = dinv[row];
            unsigned short* op = out + row * 128 + lhi * 4;
#pragma unroll
            for (int n = 0; n < 8; n++) {
                f32x4 v = acc[g][n];
                ushort4 pk;
                pk.x = f2bf(v[0] * dv);
                pk.y = f2bf(v[1] * dv);
                pk.z = f2bf(v[2] * dv);
                pk.w = f2bf(v[3] * dv);
                *reinterpret_cast<ushort4*>(op + n * 16) = pk;
            }
        }
    }
}

// ---------------------------------------------------------------------------
// CSR gather over bf16 rows: one wave per node, lane holds 2 cols (1 dword).
// 4-edge unroll with independent accumulators for memory-level parallelism.
// ---------------------------------------------------------------------------
template <bool RELU>
__global__ void gather16(const unsigned int* __restrict__ hs, const float* __restrict__ dinv,
                         const int* __restrict__ row_ptr, const int* __restrict__ edge_src,
                         const float* __restrict__ bias, unsigned int* __restrict__ out, int n) {
    int node = blockIdx.x * 4 + (threadIdx.x >> 6);
    if (node >= n) return;
    int lane = threadIdx.x & 63;
    int beg = row_ptr[node], end = row_ptr[node + 1];
    unsigned int sv = hs[(size_t)node * 64 + lane];
    float ax = bfl(sv), ay = bfh(sv);
    float bx = 0.f, by = 0.f, cx = 0.f, cy = 0.f, dx = 0.f, dy = 0.f;
    int e = beg;
    for (; e + 4 <= end; e += 4) {
        int s0 = edge_src[e], s1 = edge_src[e + 1], s2 = edge_src[e + 2], s3 = edge_src[e + 3];
        unsigned int v0 = hs[(size_t)s0 * 64 + lane];
        unsigned int v1 = hs[(size_t)s1 * 64 + lane];
        unsigned int v2 = hs[(size_t)s2 * 64 + lane];
        unsigned int v3 = hs[(size_t)s3 * 64 + lane];
        ax += bfl(v0); ay += bfh(v0);
        bx += bfl(v1); by += bfh(v1);
        cx += bfl(v2); cy += bfh(v2);
        dx += bfl(v3); dy += bfh(v3);
    }
    for (; e < end; e++) {
        unsigned int v = hs[(size_t)edge_src[e] * 64 + lane];
        ax += bfl(v); ay += bfh(v);
    }
    ax += bx + cx + dx;
    ay += by + cy + dy;
    float dv = dinv[node];
    float2 b = *reinterpret_cast<const float2*>(bias + lane * 2);
    ax = fmaf(ax, dv, b.x);
    ay = fmaf(ay, dv, b.y);
    if (RELU) { ax = fmaxf(ax, 0.f); ay = fmaxf(ay, 0.f); }
    out[(size_t)node * 64 + lane] = ((unsigned int)f2bf(ay) << 16) | f2bf(ax);
}

// final: t rows = [tm(64) | ts(64)] bf16 -> zm, zs fp32
__global__ void gather_dual(const unsigned int* __restrict__ hs, const float* __restrict__ dinv,
                            const int* __restrict__ row_ptr, const int* __restrict__ edge_src,
                            const float* __restrict__ bm, const float* __restrict__ bs,
                            float2* __restrict__ zm, float2* __restrict__ zs, int n) {
    int node = blockIdx.x * 4 + (threadIdx.x >> 6);
    if (node >= n) return;
    int lane = threadIdx.x & 63;
    int beg = row_ptr[node], end = row_ptr[node + 1];
    unsigned int sv = hs[(size_t)node * 64 + lane];
    float ax = bfl(sv), ay = bfh(sv);
    float bx = 0.f, by = 0.f, cx = 0.f, cy = 0.f, dx = 0.f, dy = 0.f;
    int e = beg;
    for (; e + 4 <= end; e += 4) {
        int s0 = edge_src[e], s1 = edge_src[e + 1], s2 = edge_src[e + 2], s3 = edge_src[e + 3];
        unsigned int v0 = hs[(size_t)s0 * 64 + lane];
        unsigned int v1 = hs[(size_t)s1 * 64 + lane];
        unsigned int v2 = hs[(size_t)s2 * 64 + lane];
        unsigned int v3 = hs[(size_t)s3 * 64 + lane];
        ax += bfl(v0); ay += bfh(v0);
        bx += bfl(v1); by += bfh(v1);
        cx += bfl(v2); cy += bfh(v2);
        dx += bfl(v3); dy += bfh(v3);
    }
    for (; e < end; e++) {
        unsigned int v = hs[(size_t)edge_src[e] * 64 + lane];
        ax += bfl(v); ay += bfh(v);
    }
    ax += bx + cx + dx;
    ay += by + cy + dy;
    float dv = dinv[node];
    if (lane < 32) {
        float2 b = *reinterpret_cast<const float2*>(bm + lane * 2);
        zm[(size_t)node * 32 + lane] = make_float2(fmaf(ax, dv, b.x), fmaf(ay, dv, b.y));
    } else {
        int l = lane - 32;
        float2 b = *reinterpret_cast<const float2*>(bs + l * 2);
        zs[(size_t)node * 32 + l] = make_float2(fmaf(ax, dv, b.x), fmaf(ay, dv, b.y));
    }
}

// ---------------------------------------------------------------------------

extern "C" void kernel_launch(void* const* d_in, const int* in_sizes, int n_in,
                              void* d_out, int out_size, void* d_ws, size_t ws_size,
                              hipStream_t stream) {
    const float* x     = (const float*)d_in[0];
    const float* noise = (const float*)d_in[1];
    const int*   ei    = (const int*)d_in[2];
    const float* gamma = (const float*)d_in[3];
    const float* beta  = (const float*)d_in[4];
    const float* W1    = (const float*)d_in[5];
    const float* b1    = (const float*)d_in[6];
    const float* W2    = (const float*)d_in[7];
    const float* b2    = (const float*)d_in[8];
    const float* Wm    = (const float*)d_in[9];
    const float* bm    = (const float*)d_in[10];
    const float* Ws    = (const float*)d_in[11];
    const float* bs    = (const float*)d_in[12];

    const int N  = in_sizes[0] / 128;
    const int E  = in_sizes[2] / 2;
    const int nb = (N + SCAN_ELEMS - 1) / SCAN_ELEMS;

    auto align256 = [](size_t b) { return (b + 255) & ~(size_t)255; };
    char* p = (char*)d_ws;
    int* cnt      = (int*)p;  p += align256((size_t)N * 4);
    int* row_ptr  = (int*)p;  p += align256((size_t)(N + 1) * 4);
    int* edge_src = (int*)p;  p += align256((size_t)E * 4);
    int* bsums    = (int*)p;  p += align256((size_t)nb * 4);
    float* dinv   = (float*)p; p += align256((size_t)N * 4);
    float* stats  = (float*)p; p += align256(512 * 4);
    unsigned short* Wt1 = (unsigned short*)p; p += align256(128 * 128 * 2);
    unsigned short* Wt2 = (unsigned short*)p; p += align256(128 * 384 * 2);
    unsigned short* Wtc = (unsigned short*)p; p += align256(128 * 256 * 2);
    unsigned short* xb16 = (unsigned short*)p; p += align256((size_t)N * 128 * 2);
    unsigned short* n16  = (unsigned short*)p; p += align256((size_t)N * 128 * 2);  // noise, then hs3
    unsigned short* h16  = (unsigned short*)p; p += align256((size_t)N * 128 * 2);  // h1, then h2

    float* colsum   = stats;
    float* colsumsq = stats + 128;
    float* scale    = stats + 256;
    float* shift    = stats + 384;

    float* dout = (float*)d_out;                       // N*128 fp32
    unsigned short* hs12 = (unsigned short*)d_out;     // conv1/2 hs scratch (bf16, fits)
    unsigned short* hs3  = n16;                        // noise dead after conv2
    float2* zm = (float2*)dout;                        // [N*32] float2
    float2* zs = (float2*)(dout + (size_t)N * 64);

    const int gblocks = (N + 127) / 128;
    const int nblocks4 = (N + 3) / 4;

    // --- graph structure + BN stats + conversions ---
    zero_i32<<<(N + 255) / 256, 256, 0, stream>>>(cnt, N);
    zero_i32<<<2, 256, 0, stream>>>((int*)stats, 512);
    count_deg<<<(E + 255) / 256, 256, 0, stream>>>(ei, cnt, E);
    bn_stats<<<512, 256, 0, stream>>>((const float4*)x, colsum, colsumsq, N);
    bn_finalize<<<1, 128, 0, stream>>>(colsum, colsumsq, gamma, beta, scale, shift, 1.0f / (float)N);
    scan_blocks<<<nb, SCAN_BLK, 0, stream>>>(cnt, row_ptr, bsums, N);
    scan_bsums<<<1, 64, 0, stream>>>(bsums, nb);
    scan_add<<<(N + 255) / 256, 256, 0, stream>>>(row_ptr, bsums, N, E);
    dinv_from_cnt<<<(N + 255) / 256, 256, 0, stream>>>(cnt, dinv, N);
    fill_edges<<<(E + 255) / 256, 256, 0, stream>>>(ei, row_ptr, cnt, edge_src, E);
    convert_inputs<<<(N * 32 + 255) / 256, 256, 0, stream>>>(
        (const float4*)x, (const float4*)noise, scale, shift,
        (ushort4*)xb16, (ushort4*)n16, N * 32);
    transpose_w<<<(128 * 128 + 255) / 256, 256, 0, stream>>>(W1, Wt1, 128, 128);
    transpose_w<<<(384 * 128 + 255) / 256, 256, 0, stream>>>(W2, Wt2, 384, 128);
    transpose_w<<<(256 * 64 + 255) / 256, 256, 0, stream>>>(Wm, Wtc, 256, 64);
    transpose_w<<<(256 * 64 + 255) / 256, 256, 0, stream>>>(Ws, Wtc + 64 * 256, 256, 64);

    // conv1
    gemm_mfma<1><<<gblocks, 256, 0, stream>>>(xb16, nullptr, nullptr, Wt1, dinv, hs12, N);
    gather16<true><<<nblocks4, 256, 0, stream>>>((const unsigned int*)hs12, dinv, row_ptr,
                                                 edge_src, b1, (unsigned int*)h16, N);
    // conv2
    gemm_mfma<3><<<gblocks, 256, 0, stream>>>(xb16, n16, h16, Wt2, dinv, hs12, N);
    gather16<true><<<nblocks4, 256, 0, stream>>>((const unsigned int*)hs12, dinv, row_ptr,
                                                 edge_src, b2, (unsigned int*)h16, N);
    // mean/logstd fused (hs -> n16 slot; d_out now gets final fp32 outputs)
    gemm_mfma<2><<<gblocks, 256, 0, stream>>>(xb16, h16, nullptr, Wtc, dinv, hs3, N);
    gather_dual<<<nblocks4, 256, 0, stream>>>((const unsigned int*)hs3, dinv, row_ptr,
                                              edge_src, bm, bs, zm, zs, N);
}

// Round 5
// 475.537 us; speedup vs baseline: 5.2084x; 1.0395x over previous
//
#include <hip/hip_runtime.h>
#include <math.h>

// ---------------------------------------------------------------------------
// GCN encoder forward, bf16 MFMA formulation:
//   CSR build (hist->scan->fill) ; BN stats (fp32, vectorized)
//   xb16 = bn(x) in bf16 ; noise16 = bf16(noise) ; Wt = W^T in bf16
//   hs16 = (concat srcs @ W) * dinv[row]   (MFMA gemm, bf16 out)
//   out[d] = act(dinv[d]*(sum_in hs16[src] + hs16[d]) + bias)  (CSR gather,
//            8-edge unrolled for memory-level parallelism)
// GEMM: 64row x 128col block, 4 waves 2x2 (wave 32x64), high occupancy.
// ---------------------------------------------------------------------------

typedef short bf16x8 __attribute__((ext_vector_type(8)));
typedef float f32x4 __attribute__((ext_vector_type(4)));

__device__ inline unsigned short f2bf(float f) {  // RNE
    unsigned int u = __builtin_bit_cast(unsigned int, f);
    u += 0x7fff + ((u >> 16) & 1);
    return (unsigned short)(u >> 16);
}
__device__ inline float bfl(unsigned int u) { return __builtin_bit_cast(float, u << 16); }
__device__ inline float bfh(unsigned int u) { return __builtin_bit_cast(float, u & 0xffff0000u); }

__global__ void zero_i32(int* __restrict__ p, int n) {
    int i = blockIdx.x * blockDim.x + threadIdx.x;
    if (i < n) p[i] = 0;
}

__global__ void count_deg(const int* __restrict__ ei, int* __restrict__ cnt, int E) {
    int e = blockIdx.x * blockDim.x + threadIdx.x;
    if (e < E) atomicAdd(&cnt[ei[E + e]], 1);
}

__global__ void dinv_from_cnt(const int* __restrict__ cnt, float* __restrict__ dinv, int n) {
    int i = blockIdx.x * blockDim.x + threadIdx.x;
    if (i < n) dinv[i] = rsqrtf((float)cnt[i] + 1.0f);   // +1 self-loop
}

#define SCAN_BLK 256
#define SCAN_ELEMS 1024

__global__ void scan_blocks(const int* __restrict__ cnt, int* __restrict__ out,
                            int* __restrict__ bsums, int n) {
    __shared__ int lds[SCAN_BLK];
    int base = blockIdx.x * SCAN_ELEMS;
    int t = threadIdx.x;
    int v[4];
    int s = 0;
#pragma unroll
    for (int j = 0; j < 4; j++) {
        int i = base + t * 4 + j;
        v[j] = s;
        s += (i < n) ? cnt[i] : 0;
    }
    lds[t] = s;
    __syncthreads();
    for (int off = 1; off < SCAN_BLK; off <<= 1) {
        int val = (t >= off) ? lds[t - off] : 0;
        __syncthreads();
        lds[t] += val;
        __syncthreads();
    }
    int excl = (t == 0) ? 0 : lds[t - 1];
#pragma unroll
    for (int j = 0; j < 4; j++) {
        int i = base + t * 4 + j;
        if (i < n) out[i] = excl + v[j];
    }
    if (t == SCAN_BLK - 1) bsums[blockIdx.x] = lds[t];
}

__global__ void scan_bsums(int* __restrict__ bsums, int nb) {
    if (threadIdx.x == 0 && blockIdx.x == 0) {
        int acc = 0;
        for (int i = 0; i < nb; i++) { int c = bsums[i]; bsums[i] = acc; acc += c; }
    }
}

__global__ void scan_add(int* __restrict__ row_ptr, const int* __restrict__ bsums, int n, int E) {
    int i = blockIdx.x * blockDim.x + threadIdx.x;
    if (i < n) row_ptr[i] += bsums[i / SCAN_ELEMS];
    if (i == 0) row_ptr[n] = E;
}

__global__ void fill_edges(const int* __restrict__ ei, const int* __restrict__ row_ptr,
                           int* __restrict__ cnt, int* __restrict__ edge_src, int E) {
    int e = blockIdx.x * blockDim.x + threadIdx.x;
    if (e >= E) return;
    int s = ei[e], d = ei[E + e];
    int off = atomicSub(&cnt[d], 1) - 1;
    edge_src[row_ptr[d] + off] = s;
}

// ---- BN statistics: 256 thr = 8 row-slices x 32 col-groups(float4) --------
__global__ __launch_bounds__(256) void bn_stats(const float4* __restrict__ x4,
                                                float* __restrict__ colsum,
                                                float* __restrict__ colsumsq, int n) {
    int t = threadIdx.x;
    int cg = t & 31;
    int rs = t >> 5;
    float4 s = make_float4(0.f, 0.f, 0.f, 0.f);
    float4 q = make_float4(0.f, 0.f, 0.f, 0.f);
    const int stride = gridDim.x * 16;
    for (int r = blockIdx.x * 16 + rs * 2; r < n; r += stride) {
        float4 v = x4[(size_t)r * 32 + cg];
        s.x += v.x; s.y += v.y; s.z += v.z; s.w += v.w;
        q.x = fmaf(v.x, v.x, q.x); q.y = fmaf(v.y, v.y, q.y);
        q.z = fmaf(v.z, v.z, q.z); q.w = fmaf(v.w, v.w, q.w);
        int r2 = r + 1;
        if (r2 < n) {
            float4 w = x4[(size_t)r2 * 32 + cg];
            s.x += w.x; s.y += w.y; s.z += w.z; s.w += w.w;
            q.x = fmaf(w.x, w.x, q.x); q.y = fmaf(w.y, w.y, q.y);
            q.z = fmaf(w.z, w.z, q.z); q.w = fmaf(w.w, w.w, q.w);
        }
    }
    __shared__ float4 lds[2][8][32];
    lds[0][rs][cg] = s;
    lds[1][rs][cg] = q;
    __syncthreads();
    if (t < 64) {
        int which = t >> 5;
        int c = t & 31;
        float4 a = lds[which][0][c];
#pragma unroll
        for (int i = 1; i < 8; i++) {
            float4 b = lds[which][i][c];
            a.x += b.x; a.y += b.y; a.z += b.z; a.w += b.w;
        }
        float* dst = which ? colsumsq : colsum;
        atomicAdd(&dst[c * 4 + 0], a.x);
        atomicAdd(&dst[c * 4 + 1], a.y);
        atomicAdd(&dst[c * 4 + 2], a.z);
        atomicAdd(&dst[c * 4 + 3], a.w);
    }
}

__global__ void bn_finalize(const float* __restrict__ colsum, const float* __restrict__ colsumsq,
                            const float* __restrict__ gamma, const float* __restrict__ beta,
                            float* __restrict__ scale, float* __restrict__ shift, float invN) {
    int c = threadIdx.x;
    float mu = colsum[c] * invN;
    float var = colsumsq[c] * invN - mu * mu;
    float sc = gamma[c] / sqrtf(var + 1e-5f);
    scale[c] = sc;
    shift[c] = beta[c] - mu * sc;
}

// x -> bn -> bf16 ; noise -> bf16. One pass, float4 in / ushort4 out.
__global__ void convert_inputs(const float4* __restrict__ x4, const float4* __restrict__ n4,
                               const float* __restrict__ scale, const float* __restrict__ shift,
                               ushort4* __restrict__ xb, ushort4* __restrict__ nb, int total4) {
    int i = blockIdx.x * blockDim.x + threadIdx.x;
    if (i >= total4) return;
    int c4 = (i & 31) << 2;
    float4 sc = *reinterpret_cast<const float4*>(scale + c4);
    float4 sh = *reinterpret_cast<const float4*>(shift + c4);
    float4 v = x4[i];
    ushort4 o;
    o.x = f2bf(fmaf(v.x, sc.x, sh.x));
    o.y = f2bf(fmaf(v.y, sc.y, sh.y));
    o.z = f2bf(fmaf(v.z, sc.z, sh.z));
    o.w = f2bf(fmaf(v.w, sc.w, sh.w));
    xb[i] = o;
    float4 w = n4[i];
    ushort4 p;
    p.x = f2bf(w.x); p.y = f2bf(w.y); p.z = f2bf(w.z); p.w = f2bf(w.w);
    nb[i] = p;
}

// Wt[c][k] = bf16(W[k][c]); Wt row stride = K
__global__ void transpose_w(const float* __restrict__ W, unsigned short* __restrict__ Wt,
                            int K, int C) {
    int i = blockIdx.x * blockDim.x + threadIdx.x;
    if (i >= K * C) return;
    int k = i / C, c = i % C;
    Wt[(size_t)c * K + k] = f2bf(W[i]);
}

// ---------------------------------------------------------------------------
// MFMA GEMM: hs[M x 128] = (sum_s A_s[M x 128] @ W[s*128:, :]) * dinv[row]
// Block 64 rows x 128 cols, 4 waves 2x2; wave tile 32 rows x 64 cols.
// ---------------------------------------------------------------------------
template <int NSRC>
__global__ __launch_bounds__(256, 4) void gemm_mfma(
    const unsigned short* __restrict__ A0, const unsigned short* __restrict__ A1,
    const unsigned short* __restrict__ A2,
    const unsigned short* __restrict__ Wt,   // [128 cols][NSRC*128 k]
    const float* __restrict__ dinv, unsigned short* __restrict__ out, int M)
{
    constexpr int KTOT = NSRC * 128;
    const int lane = threadIdx.x & 63;
    const int wid  = threadIdx.x >> 6;
    const int wr   = wid >> 1, wc = wid & 1;
    const int l15  = lane & 15, lhi = lane >> 4;
    const int c0   = wc * 64;
    const long r0 = (long)blockIdx.x * 64 + wr * 32 + l15;
    const long r1 = r0 + 16;
    const bool v0 = r0 < M, v1 = r1 < M;

    f32x4 acc[2][4];
#pragma unroll
    for (int g = 0; g < 2; g++)
#pragma unroll
        for (int n = 0; n < 4; n++)
            acc[g][n] = (f32x4){0.f, 0.f, 0.f, 0.f};

    const bf16x8 zero8 = (bf16x8){0,0,0,0,0,0,0,0};
    const unsigned short* __restrict__ srcs[3] = {A0, A1, A2};
#pragma unroll
    for (int s = 0; s < NSRC; s++) {
        const unsigned short* __restrict__ A = srcs[s];
        const unsigned short* a0p = A + r0 * 128 + lhi * 8;
        const unsigned short* a1p = A + r1 * 128 + lhi * 8;
#pragma unroll
        for (int kc = 0; kc < 4; kc++) {
            bf16x8 a0 = v0 ? *reinterpret_cast<const bf16x8*>(a0p + kc * 32) : zero8;
            bf16x8 a1 = v1 ? *reinterpret_cast<const bf16x8*>(a1p + kc * 32) : zero8;
            const unsigned short* wp = Wt + (size_t)(c0 + l15) * KTOT + s * 128 + kc * 32 + lhi * 8;
#pragma unroll
            for (int n = 0; n < 4; n++) {
                bf16x8 w = *reinterpret_cast<const bf16x8*>(wp + (size_t)(n * 16) * KTOT);
                acc[0][n] = __builtin_amdgcn_mfma_f32_16x16x32_bf16(w, a0, acc[0][n], 0, 0, 0);
                acc[1][n] = __builtin_amdgcn_mfma_f32_16x16x32_bf16(w, a1, acc[1][n], 0, 0, 0);
            }
        }
    }

#pragma unroll
    for (int g = 0; g < 2; g++) {
        long row = g ? r1 : r0;
        if (row < M) {
            float dv = dinv[row];
            unsigned short* op = out + row * 128 + c0 + lhi * 4;
#pragma unroll
            for (int n = 0; n < 4; n++) {
                f32x4 v = acc[g][n];
                ushort4 pk;
                pk.x = f2bf(v[0] * dv);
                pk.y = f2bf(v[1] * dv);
                pk.z = f2bf(v[2] * dv);
                pk.w = f2bf(v[3] * dv);
                *reinterpret_cast<ushort4*>(op + n * 16) = pk;
            }
        }
    }
}

// ---------------------------------------------------------------------------
// CSR gather over bf16 rows: one wave per node, lane holds 2 cols (1 dword).
// 8-edge unroll with independent accumulators for memory-level parallelism.
// ---------------------------------------------------------------------------
template <bool RELU>
__global__ void gather16(const unsigned int* __restrict__ hs, const float* __restrict__ dinv,
                         const int* __restrict__ row_ptr, const int* __restrict__ edge_src,
                         const float* __restrict__ bias, unsigned int* __restrict__ out, int n) {
    int node = blockIdx.x * 4 + (threadIdx.x >> 6);
    if (node >= n) return;
    int lane = threadIdx.x & 63;
    int beg = row_ptr[node], end = row_ptr[node + 1];
    unsigned int sv = hs[(size_t)node * 64 + lane];
    float a0x = bfl(sv), a0y = bfh(sv);
    float a1x = 0.f, a1y = 0.f, a2x = 0.f, a2y = 0.f, a3x = 0.f, a3y = 0.f;
    float a4x = 0.f, a4y = 0.f, a5x = 0.f, a5y = 0.f, a6x = 0.f, a6y = 0.f, a7x = 0.f, a7y = 0.f;
    int e = beg;
    for (; e + 8 <= end; e += 8) {
        int s0 = edge_src[e],     s1 = edge_src[e + 1], s2 = edge_src[e + 2], s3 = edge_src[e + 3];
        int s4 = edge_src[e + 4], s5 = edge_src[e + 5], s6 = edge_src[e + 6], s7 = edge_src[e + 7];
        unsigned int v0 = hs[(size_t)s0 * 64 + lane];
        unsigned int v1 = hs[(size_t)s1 * 64 + lane];
        unsigned int v2 = hs[(size_t)s2 * 64 + lane];
        unsigned int v3 = hs[(size_t)s3 * 64 + lane];
        unsigned int v4 = hs[(size_t)s4 * 64 + lane];
        unsigned int v5 = hs[(size_t)s5 * 64 + lane];
        unsigned int v6 = hs[(size_t)s6 * 64 + lane];
        unsigned int v7 = hs[(size_t)s7 * 64 + lane];
        a0x += bfl(v0); a0y += bfh(v0);
        a1x += bfl(v1); a1y += bfh(v1);
        a2x += bfl(v2); a2y += bfh(v2);
        a3x += bfl(v3); a3y += bfh(v3);
        a4x += bfl(v4); a4y += bfh(v4);
        a5x += bfl(v5); a5y += bfh(v5);
        a6x += bfl(v6); a6y += bfh(v6);
        a7x += bfl(v7); a7y += bfh(v7);
    }
    if (e + 4 <= end) {
        int s0 = edge_src[e], s1 = edge_src[e + 1], s2 = edge_src[e + 2], s3 = edge_src[e + 3];
        unsigned int v0 = hs[(size_t)s0 * 64 + lane];
        unsigned int v1 = hs[(size_t)s1 * 64 + lane];
        unsigned int v2 = hs[(size_t)s2 * 64 + lane];
        unsigned int v3 = hs[(size_t)s3 * 64 + lane];
        a0x += bfl(v0); a0y += bfh(v0);
        a1x += bfl(v1); a1y += bfh(v1);
        a2x += bfl(v2); a2y += bfh(v2);
        a3x += bfl(v3); a3y += bfh(v3);
        e += 4;
    }
    for (; e < end; e++) {
        unsigned int v = hs[(size_t)edge_src[e] * 64 + lane];
        a0x += bfl(v); a0y += bfh(v);
    }
    float ax = (a0x + a1x) + (a2x + a3x) + ((a4x + a5x) + (a6x + a7x));
    float ay = (a0y + a1y) + (a2y + a3y) + ((a4y + a5y) + (a6y + a7y));
    float dv = dinv[node];
    float2 b = *reinterpret_cast<const float2*>(bias + lane * 2);
    ax = fmaf(ax, dv, b.x);
    ay = fmaf(ay, dv, b.y);
    if (RELU) { ax = fmaxf(ax, 0.f); ay = fmaxf(ay, 0.f); }
    out[(size_t)node * 64 + lane] = ((unsigned int)f2bf(ay) << 16) | f2bf(ax);
}

// final: t rows = [tm(64) | ts(64)] bf16 -> zm, zs fp32
__global__ void gather_dual(const unsigned int* __restrict__ hs, const float* __restrict__ dinv,
                            const int* __restrict__ row_ptr, const int* __restrict__ edge_src,
                            const float* __restrict__ bm, const float* __restrict__ bs,
                            float2* __restrict__ zm, float2* __restrict__ zs, int n) {
    int node = blockIdx.x * 4 + (threadIdx.x >> 6);
    if (node >= n) return;
    int lane = threadIdx.x & 63;
    int beg = row_ptr[node], end = row_ptr[node + 1];
    unsigned int sv = hs[(size_t)node * 64 + lane];
    float a0x = bfl(sv), a0y = bfh(sv);
    float a1x = 0.f, a1y = 0.f, a2x = 0.f, a2y = 0.f, a3x = 0.f, a3y = 0.f;
    float a4x = 0.f, a4y = 0.f, a5x = 0.f, a5y = 0.f, a6x = 0.f, a6y = 0.f, a7x = 0.f, a7y = 0.f;
    int e = beg;
    for (; e + 8 <= end; e += 8) {
        int s0 = edge_src[e],     s1 = edge_src[e + 1], s2 = edge_src[e + 2], s3 = edge_src[e + 3];
        int s4 = edge_src[e + 4], s5 = edge_src[e + 5], s6 = edge_src[e + 6], s7 = edge_src[e + 7];
        unsigned int v0 = hs[(size_t)s0 * 64 + lane];
        unsigned int v1 = hs[(size_t)s1 * 64 + lane];
        unsigned int v2 = hs[(size_t)s2 * 64 + lane];
        unsigned int v3 = hs[(size_t)s3 * 64 + lane];
        unsigned int v4 = hs[(size_t)s4 * 64 + lane];
        unsigned int v5 = hs[(size_t)s5 * 64 + lane];
        unsigned int v6 = hs[(size_t)s6 * 64 + lane];
        unsigned int v7 = hs[(size_t)s7 * 64 + lane];
        a0x += bfl(v0); a0y += bfh(v0);
        a1x += bfl(v1); a1y += bfh(v1);
        a2x += bfl(v2); a2y += bfh(v2);
        a3x += bfl(v3); a3y += bfh(v3);
        a4x += bfl(v4); a4y += bfh(v4);
        a5x += bfl(v5); a5y += bfh(v5);
        a6x += bfl(v6); a6y += bfh(v6);
        a7x += bfl(v7); a7y += bfh(v7);
    }
    if (e + 4 <= end) {
        int s0 = edge_src[e], s1 = edge_src[e + 1], s2 = edge_src[e + 2], s3 = edge_src[e + 3];
        unsigned int v0 = hs[(size_t)s0 * 64 + lane];
        unsigned int v1 = hs[(size_t)s1 * 64 + lane];
        unsigned int v2 = hs[(size_t)s2 * 64 + lane];
        unsigned int v3 = hs[(size_t)s3 * 64 + lane];
        a0x += bfl(v0); a0y += bfh(v0);
        a1x += bfl(v1); a1y += bfh(v1);
        a2x += bfl(v2); a2y += bfh(v2);
        a3x += bfl(v3); a3y += bfh(v3);
        e += 4;
    }
    for (; e < end; e++) {
        unsigned int v = hs[(size_t)edge_src[e] * 64 + lane];
        a0x += bfl(v); a0y += bfh(v);
    }
    float ax = (a0x + a1x) + (a2x + a3x) + ((a4x + a5x) + (a6x + a7x));
    float ay = (a0y + a1y) + (a2y + a3y) + ((a4y + a5y) + (a6y + a7y));
    float dv = dinv[node];
    if (lane < 32) {
        float2 b = *reinterpret_cast<const float2*>(bm + lane * 2);
        zm[(size_t)node * 32 + lane] = make_float2(fmaf(ax, dv, b.x), fmaf(ay, dv, b.y));
    } else {
        int l = lane - 32;
        float2 b = *reinterpret_cast<const float2*>(bs + l * 2);
        zs[(size_t)node * 32 + l] = make_float2(fmaf(ax, dv, b.x), fmaf(ay, dv, b.y));
    }
}

// ---------------------------------------------------------------------------

extern "C" void kernel_launch(void* const* d_in, const int* in_sizes, int n_in,
                              void* d_out, int out_size, void* d_ws, size_t ws_size,
                              hipStream_t stream) {
    const float* x     = (const float*)d_in[0];
    const float* noise = (const float*)d_in[1];
    const int*   ei    = (const int*)d_in[2];
    const float* gamma = (const float*)d_in[3];
    const float* beta  = (const float*)d_in[4];
    const float* W1    = (const float*)d_in[5];
    const float* b1    = (const float*)d_in[6];
    const float* W2    = (const float*)d_in[7];
    const float* b2    = (const float*)d_in[8];
    const float* Wm    = (const float*)d_in[9];
    const float* bm    = (const float*)d_in[10];
    const float* Ws    = (const float*)d_in[11];
    const float* bs    = (const float*)d_in[12];

    const int N  = in_sizes[0] / 128;
    const int E  = in_sizes[2] / 2;
    const int nb = (N + SCAN_ELEMS - 1) / SCAN_ELEMS;

    auto align256 = [](size_t b) { return (b + 255) & ~(size_t)255; };
    char* p = (char*)d_ws;
    int* cnt      = (int*)p;  p += align256((size_t)N * 4);
    int* row_ptr  = (int*)p;  p += align256((size_t)(N + 1) * 4);
    int* edge_src = (int*)p;  p += align256((size_t)E * 4);
    int* bsums    = (int*)p;  p += align256((size_t)nb * 4);
    float* dinv   = (float*)p; p += align256((size_t)N * 4);
    float* stats  = (float*)p; p += align256(512 * 4);
    unsigned short* Wt1 = (unsigned short*)p; p += align256(128 * 128 * 2);
    unsigned short* Wt2 = (unsigned short*)p; p += align256(128 * 384 * 2);
    unsigned short* Wtc = (unsigned short*)p; p += align256(128 * 256 * 2);
    unsigned short* xb16 = (unsigned short*)p; p += align256((size_t)N * 128 * 2);
    unsigned short* n16  = (unsigned short*)p; p += align256((size_t)N * 128 * 2);  // noise, then hs3
    unsigned short* h16  = (unsigned short*)p; p += align256((size_t)N * 128 * 2);  // h1, then h2

    float* colsum   = stats;
    float* colsumsq = stats + 128;
    float* scale    = stats + 256;
    float* shift    = stats + 384;

    float* dout = (float*)d_out;                       // N*128 fp32
    unsigned short* hs12 = (unsigned short*)d_out;     // conv1/2 hs scratch (bf16, fits)
    unsigned short* hs3  = n16;                        // noise dead after conv2
    float2* zm = (float2*)dout;                        // [N*32] float2
    float2* zs = (float2*)(dout + (size_t)N * 64);

    const int gblocks = (N + 63) / 64;
    const int nblocks4 = (N + 3) / 4;

    // --- graph structure + BN stats + conversions ---
    zero_i32<<<(N + 255) / 256, 256, 0, stream>>>(cnt, N);
    zero_i32<<<2, 256, 0, stream>>>((int*)stats, 512);
    count_deg<<<(E + 255) / 256, 256, 0, stream>>>(ei, cnt, E);
    bn_stats<<<512, 256, 0, stream>>>((const float4*)x, colsum, colsumsq, N);
    bn_finalize<<<1, 128, 0, stream>>>(colsum, colsumsq, gamma, beta, scale, shift, 1.0f / (float)N);
    scan_blocks<<<nb, SCAN_BLK, 0, stream>>>(cnt, row_ptr, bsums, N);
    scan_bsums<<<1, 64, 0, stream>>>(bsums, nb);
    scan_add<<<(N + 255) / 256, 256, 0, stream>>>(row_ptr, bsums, N, E);
    dinv_from_cnt<<<(N + 255) / 256, 256, 0, stream>>>(cnt, dinv, N);
    fill_edges<<<(E + 255) / 256, 256, 0, stream>>>(ei, row_ptr, cnt, edge_src, E);
    convert_inputs<<<(N * 32 + 255) / 256, 256, 0, stream>>>(
        (const float4*)x, (const float4*)noise, scale, shift,
        (ushort4*)xb16, (ushort4*)n16, N * 32);
    transpose_w<<<(128 * 128 + 255) / 256, 256, 0, stream>>>(W1, Wt1, 128, 128);
    transpose_w<<<(384 * 128 + 255) / 256, 256, 0, stream>>>(W2, Wt2, 384, 128);
    transpose_w<<<(256 * 64 + 255) / 256, 256, 0, stream>>>(Wm, Wtc, 256, 64);
    transpose_w<<<(256 * 64 + 255) / 256, 256, 0, stream>>>(Ws, Wtc + 64 * 256, 256, 64);

    // conv1
    gemm_mfma<1><<<gblocks, 256, 0, stream>>>(xb16, nullptr, nullptr, Wt1, dinv, hs12, N);
    gather16<true><<<nblocks4, 256, 0, stream>>>((const unsigned int*)hs12, dinv, row_ptr,
                                                 edge_src, b1, (unsigned int*)h16, N);
    // conv2
    gemm_mfma<3><<<gblocks, 256, 0, stream>>>(xb16, n16, h16, Wt2, dinv, hs12, N);
    gather16<true><<<nblocks4, 256, 0, stream>>>((const unsigned int*)hs12, dinv, row_ptr,
                                                 edge_src, b2, (unsigned int*)h16, N);
    // mean/logstd fused (hs -> n16 slot; d_out now gets final fp32 outputs)
    gemm_mfma<2><<<gblocks, 256, 0, stream>>>(xb16, h16, nullptr, Wtc, dinv, hs3, N);
    gather_dual<<<nblocks4, 256, 0, stream>>>((const unsigned int*)hs3, dinv, row_ptr,
                                              edge_src, bm, bs, zm, zs, N);
}

// Round 6
// 418.089 us; speedup vs baseline: 5.9241x; 1.1374x over previous
//
#include <hip/hip_runtime.h>
#include <math.h>

// ---------------------------------------------------------------------------
// GCN encoder forward, bf16 MFMA formulation:
//   CSR build (hist->scan->fill) ; BN stats (fp32, partials + reduce)
//   xb16 = bn(x) in bf16 ; noise16 = bf16(noise) ; Wt = W^T in bf16
//   hs16 = (concat srcs @ W) * dinv[row]   (MFMA gemm, bf16 out)
//   out[d] = act(dinv[d]*(sum_in hs16[src] + hs16[d]) + bias)
//   Gather: 16 lanes x uint4 cover a row; 4 sub-groups stride the edge list.
// ---------------------------------------------------------------------------

typedef short bf16x8 __attribute__((ext_vector_type(8)));
typedef float f32x4 __attribute__((ext_vector_type(4)));

#define BN_G 1024

__device__ inline unsigned short f2bf(float f) {  // RNE
    unsigned int u = __builtin_bit_cast(unsigned int, f);
    u += 0x7fff + ((u >> 16) & 1);
    return (unsigned short)(u >> 16);
}
__device__ inline float bfl(unsigned int u) { return __builtin_bit_cast(float, u << 16); }
__device__ inline float bfh(unsigned int u) { return __builtin_bit_cast(float, u & 0xffff0000u); }
__device__ inline unsigned int pack2(float lo, float hi) {
    return ((unsigned int)f2bf(hi) << 16) | f2bf(lo);
}
__device__ inline void acc8(float* a, uint4 v) {
    a[0] += bfl(v.x); a[1] += bfh(v.x);
    a[2] += bfl(v.y); a[3] += bfh(v.y);
    a[4] += bfl(v.z); a[5] += bfh(v.z);
    a[6] += bfl(v.w); a[7] += bfh(v.w);
}

__global__ void zero_i32(int* __restrict__ p, int n) {
    int i = blockIdx.x * blockDim.x + threadIdx.x;
    if (i < n) p[i] = 0;
}

__global__ void count_deg(const int* __restrict__ ei, int* __restrict__ cnt, int E) {
    int e = blockIdx.x * blockDim.x + threadIdx.x;
    if (e < E) atomicAdd(&cnt[ei[E + e]], 1);
}

__global__ void dinv_from_cnt(const int* __restrict__ cnt, float* __restrict__ dinv, int n) {
    int i = blockIdx.x * blockDim.x + threadIdx.x;
    if (i < n) dinv[i] = rsqrtf((float)cnt[i] + 1.0f);   // +1 self-loop
}

#define SCAN_BLK 256
#define SCAN_ELEMS 1024

__global__ void scan_blocks(const int* __restrict__ cnt, int* __restrict__ out,
                            int* __restrict__ bsums, int n) {
    __shared__ int lds[SCAN_BLK];
    int base = blockIdx.x * SCAN_ELEMS;
    int t = threadIdx.x;
    int v[4];
    int s = 0;
#pragma unroll
    for (int j = 0; j < 4; j++) {
        int i = base + t * 4 + j;
        v[j] = s;
        s += (i < n) ? cnt[i] : 0;
    }
    lds[t] = s;
    __syncthreads();
    for (int off = 1; off < SCAN_BLK; off <<= 1) {
        int val = (t >= off) ? lds[t - off] : 0;
        __syncthreads();
        lds[t] += val;
        __syncthreads();
    }
    int excl = (t == 0) ? 0 : lds[t - 1];
#pragma unroll
    for (int j = 0; j < 4; j++) {
        int i = base + t * 4 + j;
        if (i < n) out[i] = excl + v[j];
    }
    if (t == SCAN_BLK - 1) bsums[blockIdx.x] = lds[t];
}

__global__ void scan_bsums(int* __restrict__ bsums, int nb) {
    if (threadIdx.x == 0 && blockIdx.x == 0) {
        int acc = 0;
        for (int i = 0; i < nb; i++) { int c = bsums[i]; bsums[i] = acc; acc += c; }
    }
}

__global__ void scan_add(int* __restrict__ row_ptr, const int* __restrict__ bsums, int n, int E) {
    int i = blockIdx.x * blockDim.x + threadIdx.x;
    if (i < n) row_ptr[i] += bsums[i / SCAN_ELEMS];
    if (i == 0) row_ptr[n] = E;
}

__global__ void fill_edges(const int* __restrict__ ei, const int* __restrict__ row_ptr,
                           int* __restrict__ cnt, int* __restrict__ edge_src, int E) {
    int e = blockIdx.x * blockDim.x + threadIdx.x;
    if (e >= E) return;
    int s = ei[e], d = ei[E + e];
    int off = atomicSub(&cnt[d], 1) - 1;
    edge_src[row_ptr[d] + off] = s;
}

// ---- BN statistics: 4-deep row unroll, non-atomic partials ----------------
__global__ __launch_bounds__(256) void bn_stats(const float4* __restrict__ x4,
                                                float* __restrict__ partials, int n) {
    int t = threadIdx.x;
    int cg = t & 31;          // column group (float4)
    int rs = t >> 5;          // row slice 0..7, 4 rows each
    float4 s = make_float4(0.f, 0.f, 0.f, 0.f);
    float4 q = make_float4(0.f, 0.f, 0.f, 0.f);
    const float4 z4 = make_float4(0.f, 0.f, 0.f, 0.f);
    const int stride = BN_G * 32;
    for (int r0 = blockIdx.x * 32 + rs * 4; r0 < n; r0 += stride) {
        float4 v0 = x4[(size_t)r0 * 32 + cg];
        float4 v1 = (r0 + 1 < n) ? x4[(size_t)(r0 + 1) * 32 + cg] : z4;
        float4 v2 = (r0 + 2 < n) ? x4[(size_t)(r0 + 2) * 32 + cg] : z4;
        float4 v3 = (r0 + 3 < n) ? x4[(size_t)(r0 + 3) * 32 + cg] : z4;
        s.x += v0.x + v1.x + v2.x + v3.x;
        s.y += v0.y + v1.y + v2.y + v3.y;
        s.z += v0.z + v1.z + v2.z + v3.z;
        s.w += v0.w + v1.w + v2.w + v3.w;
        q.x = fmaf(v0.x, v0.x, fmaf(v1.x, v1.x, fmaf(v2.x, v2.x, fmaf(v3.x, v3.x, q.x))));
        q.y = fmaf(v0.y, v0.y, fmaf(v1.y, v1.y, fmaf(v2.y, v2.y, fmaf(v3.y, v3.y, q.y))));
        q.z = fmaf(v0.z, v0.z, fmaf(v1.z, v1.z, fmaf(v2.z, v2.z, fmaf(v3.z, v3.z, q.z))));
        q.w = fmaf(v0.w, v0.w, fmaf(v1.w, v1.w, fmaf(v2.w, v2.w, fmaf(v3.w, v3.w, q.w))));
    }
    __shared__ float4 lds[2][8][32];
    lds[0][rs][cg] = s;
    lds[1][rs][cg] = q;
    __syncthreads();
    if (t < 64) {
        int which = t >> 5;   // 0: sum, 1: sumsq
        int c = t & 31;
        float4 a = lds[which][0][c];
#pragma unroll
        for (int i = 1; i < 8; i++) {
            float4 b = lds[which][i][c];
            a.x += b.x; a.y += b.y; a.z += b.z; a.w += b.w;
        }
        int base = which * 128 + c * 4;
        partials[(size_t)(base + 0) * BN_G + blockIdx.x] = a.x;
        partials[(size_t)(base + 1) * BN_G + blockIdx.x] = a.y;
        partials[(size_t)(base + 2) * BN_G + blockIdx.x] = a.z;
        partials[(size_t)(base + 3) * BN_G + blockIdx.x] = a.w;
    }
}

// one block per output element c in [0,256): stats[c] = sum over BN_G partials
__global__ void bn_reduce(const float4* __restrict__ partials4, float* __restrict__ stats) {
    __shared__ float red[256];
    int c = blockIdx.x, t = threadIdx.x;
    float4 v = partials4[(size_t)c * (BN_G / 4) + t];
    red[t] = v.x + v.y + v.z + v.w;
    __syncthreads();
    for (int off = 128; off > 0; off >>= 1) {
        if (t < off) red[t] += red[t + off];
        __syncthreads();
    }
    if (t == 0) stats[c] = red[0];
}

__global__ void bn_finalize(const float* __restrict__ colsum, const float* __restrict__ colsumsq,
                            const float* __restrict__ gamma, const float* __restrict__ beta,
                            float* __restrict__ scale, float* __restrict__ shift, float invN) {
    int c = threadIdx.x;
    float mu = colsum[c] * invN;
    float var = colsumsq[c] * invN - mu * mu;
    float sc = gamma[c] / sqrtf(var + 1e-5f);
    scale[c] = sc;
    shift[c] = beta[c] - mu * sc;
}

// x -> bn -> bf16 ; noise -> bf16. One pass, float4 in / ushort4 out.
__global__ void convert_inputs(const float4* __restrict__ x4, const float4* __restrict__ n4,
                               const float* __restrict__ scale, const float* __restrict__ shift,
                               ushort4* __restrict__ xb, ushort4* __restrict__ nb, int total4) {
    int i = blockIdx.x * blockDim.x + threadIdx.x;
    if (i >= total4) return;
    int c4 = (i & 31) << 2;
    float4 sc = *reinterpret_cast<const float4*>(scale + c4);
    float4 sh = *reinterpret_cast<const float4*>(shift + c4);
    float4 v = x4[i];
    ushort4 o;
    o.x = f2bf(fmaf(v.x, sc.x, sh.x));
    o.y = f2bf(fmaf(v.y, sc.y, sh.y));
    o.z = f2bf(fmaf(v.z, sc.z, sh.z));
    o.w = f2bf(fmaf(v.w, sc.w, sh.w));
    xb[i] = o;
    float4 w = n4[i];
    ushort4 p;
    p.x = f2bf(w.x); p.y = f2bf(w.y); p.z = f2bf(w.z); p.w = f2bf(w.w);
    nb[i] = p;
}

// Wt[c][k] = bf16(W[k][c]); Wt row stride = K
__global__ void transpose_w(const float* __restrict__ W, unsigned short* __restrict__ Wt,
                            int K, int C) {
    int i = blockIdx.x * blockDim.x + threadIdx.x;
    if (i >= K * C) return;
    int k = i / C, c = i % C;
    Wt[(size_t)c * K + k] = f2bf(W[i]);
}

// ---------------------------------------------------------------------------
// MFMA GEMM: hs[M x 128] = (sum_s A_s[M x 128] @ W[s*128:, :]) * dinv[row]
// Block 64 rows x 128 cols, 4 waves 2x2; wave tile 32 rows x 64 cols.
// ---------------------------------------------------------------------------
template <int NSRC>
__global__ __launch_bounds__(256, 4) void gemm_mfma(
    const unsigned short* __restrict__ A0, const unsigned short* __restrict__ A1,
    const unsigned short* __restrict__ A2,
    const unsigned short* __restrict__ Wt,   // [128 cols][NSRC*128 k]
    const float* __restrict__ dinv, unsigned short* __restrict__ out, int M)
{
    constexpr int KTOT = NSRC * 128;
    const int lane = threadIdx.x & 63;
    const int wid  = threadIdx.x >> 6;
    const int wr   = wid >> 1, wc = wid & 1;
    const int l15  = lane & 15, lhi = lane >> 4;
    const int c0   = wc * 64;
    const long r0 = (long)blockIdx.x * 64 + wr * 32 + l15;
    const long r1 = r0 + 16;
    const bool v0 = r0 < M, v1 = r1 < M;

    f32x4 acc[2][4];
#pragma unroll
    for (int g = 0; g < 2; g++)
#pragma unroll
        for (int n = 0; n < 4; n++)
            acc[g][n] = (f32x4){0.f, 0.f, 0.f, 0.f};

    const bf16x8 zero8 = (bf16x8){0,0,0,0,0,0,0,0};
    const unsigned short* __restrict__ srcs[3] = {A0, A1, A2};
#pragma unroll
    for (int s = 0; s < NSRC; s++) {
        const unsigned short* __restrict__ A = srcs[s];
        const unsigned short* a0p = A + r0 * 128 + lhi * 8;
        const unsigned short* a1p = A + r1 * 128 + lhi * 8;
#pragma unroll
        for (int kc = 0; kc < 4; kc++) {
            bf16x8 a0 = v0 ? *reinterpret_cast<const bf16x8*>(a0p + kc * 32) : zero8;
            bf16x8 a1 = v1 ? *reinterpret_cast<const bf16x8*>(a1p + kc * 32) : zero8;
            const unsigned short* wp = Wt + (size_t)(c0 + l15) * KTOT + s * 128 + kc * 32 + lhi * 8;
#pragma unroll
            for (int n = 0; n < 4; n++) {
                bf16x8 w = *reinterpret_cast<const bf16x8*>(wp + (size_t)(n * 16) * KTOT);
                acc[0][n] = __builtin_amdgcn_mfma_f32_16x16x32_bf16(w, a0, acc[0][n], 0, 0, 0);
                acc[1][n] = __builtin_amdgcn_mfma_f32_16x16x32_bf16(w, a1, acc[1][n], 0, 0, 0);
            }
        }
    }

#pragma unroll
    for (int g = 0; g < 2; g++) {
        long row = g ? r1 : r0;
        if (row < M) {
            float dv = dinv[row];
            unsigned short* op = out + row * 128 + c0 + lhi * 4;
#pragma unroll
            for (int n = 0; n < 4; n++) {
                f32x4 v = acc[g][n];
                ushort4 pk;
                pk.x = f2bf(v[0] * dv);
                pk.y = f2bf(v[1] * dv);
                pk.z = f2bf(v[2] * dv);
                pk.w = f2bf(v[3] * dv);
                *reinterpret_cast<ushort4*>(op + n * 16) = pk;
            }
        }
    }
}

// ---------------------------------------------------------------------------
// CSR gather: one wave per node; 16 lanes x uint4 (16B) cover one 256B row;
// 4 sub-groups stride the edge list; cross-sub shuffle reduce at the end.
// ---------------------------------------------------------------------------
template <bool RELU>
__global__ void gather16(const uint4* __restrict__ hs4, const float* __restrict__ dinv,
                         const int* __restrict__ row_ptr, const int* __restrict__ edge_src,
                         const float* __restrict__ bias, uint4* __restrict__ out4, int n) {
    int node = blockIdx.x * 4 + (threadIdx.x >> 6);
    if (node >= n) return;
    int lane = threadIdx.x & 63;
    int cl = lane & 15, sub = lane >> 4;
    int beg = row_ptr[node], end = row_ptr[node + 1];
    float a0[8] = {0.f,0.f,0.f,0.f,0.f,0.f,0.f,0.f};
    float a1[8] = {0.f,0.f,0.f,0.f,0.f,0.f,0.f,0.f};
    if (sub == 0) acc8(a0, hs4[(size_t)node * 16 + cl]);   // self-loop
    int e = beg + sub;
    for (; e + 4 < end; e += 8) {
        uint4 v0 = hs4[(size_t)edge_src[e] * 16 + cl];
        uint4 v1 = hs4[(size_t)edge_src[e + 4] * 16 + cl];
        acc8(a0, v0);
        acc8(a1, v1);
    }
    if (e < end) acc8(a0, hs4[(size_t)edge_src[e] * 16 + cl]);
#pragma unroll
    for (int i = 0; i < 8; i++) a0[i] += a1[i];
#pragma unroll
    for (int i = 0; i < 8; i++) {
        a0[i] += __shfl_xor(a0[i], 16);
        a0[i] += __shfl_xor(a0[i], 32);
    }
    if (sub == 0) {
        float dv = dinv[node];
        float4 b0 = *reinterpret_cast<const float4*>(bias + cl * 8);
        float4 b1 = *reinterpret_cast<const float4*>(bias + cl * 8 + 4);
        float r0 = fmaf(a0[0], dv, b0.x), r1 = fmaf(a0[1], dv, b0.y);
        float r2 = fmaf(a0[2], dv, b0.z), r3 = fmaf(a0[3], dv, b0.w);
        float r4 = fmaf(a0[4], dv, b1.x), r5 = fmaf(a0[5], dv, b1.y);
        float r6 = fmaf(a0[6], dv, b1.z), r7 = fmaf(a0[7], dv, b1.w);
        if (RELU) {
            r0 = fmaxf(r0, 0.f); r1 = fmaxf(r1, 0.f); r2 = fmaxf(r2, 0.f); r3 = fmaxf(r3, 0.f);
            r4 = fmaxf(r4, 0.f); r5 = fmaxf(r5, 0.f); r6 = fmaxf(r6, 0.f); r7 = fmaxf(r7, 0.f);
        }
        uint4 o;
        o.x = pack2(r0, r1); o.y = pack2(r2, r3);
        o.z = pack2(r4, r5); o.w = pack2(r6, r7);
        out4[(size_t)node * 16 + cl] = o;
    }
}

// final: t rows = [tm(64) | ts(64)] bf16 -> zm, zs fp32
__global__ void gather_dual(const uint4* __restrict__ hs4, const float* __restrict__ dinv,
                            const int* __restrict__ row_ptr, const int* __restrict__ edge_src,
                            const float* __restrict__ bm, const float* __restrict__ bs,
                            float* __restrict__ zm, float* __restrict__ zs, int n) {
    int node = blockIdx.x * 4 + (threadIdx.x >> 6);
    if (node >= n) return;
    int lane = threadIdx.x & 63;
    int cl = lane & 15, sub = lane >> 4;
    int beg = row_ptr[node], end = row_ptr[node + 1];
    float a0[8] = {0.f,0.f,0.f,0.f,0.f,0.f,0.f,0.f};
    float a1[8] = {0.f,0.f,0.f,0.f,0.f,0.f,0.f,0.f};
    if (sub == 0) acc8(a0, hs4[(size_t)node * 16 + cl]);
    int e = beg + sub;
    for (; e + 4 < end; e += 8) {
        uint4 v0 = hs4[(size_t)edge_src[e] * 16 + cl];
        uint4 v1 = hs4[(size_t)edge_src[e + 4] * 16 + cl];
        acc8(a0, v0);
        acc8(a1, v1);
    }
    if (e < end) acc8(a0, hs4[(size_t)edge_src[e] * 16 + cl]);
#pragma unroll
    for (int i = 0; i < 8; i++) a0[i] += a1[i];
#pragma unroll
    for (int i = 0; i < 8; i++) {
        a0[i] += __shfl_xor(a0[i], 16);
        a0[i] += __shfl_xor(a0[i], 32);
    }
    if (sub == 0) {
        float dv = dinv[node];
        const float* bp = (cl < 8) ? (bm + cl * 8) : (bs + (cl - 8) * 8);
        float* zp = (cl < 8) ? (zm + (size_t)node * 64 + cl * 8)
                             : (zs + (size_t)node * 64 + (cl - 8) * 8);
        float4 b0 = *reinterpret_cast<const float4*>(bp);
        float4 b1 = *reinterpret_cast<const float4*>(bp + 4);
        float4 o0 = make_float4(fmaf(a0[0], dv, b0.x), fmaf(a0[1], dv, b0.y),
                                fmaf(a0[2], dv, b0.z), fmaf(a0[3], dv, b0.w));
        float4 o1 = make_float4(fmaf(a0[4], dv, b1.x), fmaf(a0[5], dv, b1.y),
                                fmaf(a0[6], dv, b1.z), fmaf(a0[7], dv, b1.w));
        *reinterpret_cast<float4*>(zp) = o0;
        *reinterpret_cast<float4*>(zp + 4) = o1;
    }
}

// ---------------------------------------------------------------------------

extern "C" void kernel_launch(void* const* d_in, const int* in_sizes, int n_in,
                              void* d_out, int out_size, void* d_ws, size_t ws_size,
                              hipStream_t stream) {
    const float* x     = (const float*)d_in[0];
    const float* noise = (const float*)d_in[1];
    const int*   ei    = (const int*)d_in[2];
    const float* gamma = (const float*)d_in[3];
    const float* beta  = (const float*)d_in[4];
    const float* W1    = (const float*)d_in[5];
    const float* b1    = (const float*)d_in[6];
    const float* W2    = (const float*)d_in[7];
    const float* b2    = (const float*)d_in[8];
    const float* Wm    = (const float*)d_in[9];
    const float* bm    = (const float*)d_in[10];
    const float* Ws    = (const float*)d_in[11];
    const float* bs    = (const float*)d_in[12];

    const int N  = in_sizes[0] / 128;
    const int E  = in_sizes[2] / 2;
    const int nb = (N + SCAN_ELEMS - 1) / SCAN_ELEMS;

    auto align256 = [](size_t b) { return (b + 255) & ~(size_t)255; };
    char* p = (char*)d_ws;
    int* cnt      = (int*)p;  p += align256((size_t)N * 4);
    int* row_ptr  = (int*)p;  p += align256((size_t)(N + 1) * 4);
    int* edge_src = (int*)p;  p += align256((size_t)E * 4);
    int* bsums    = (int*)p;  p += align256((size_t)nb * 4);
    float* dinv   = (float*)p; p += align256((size_t)N * 4);
    float* stats  = (float*)p; p += align256(512 * 4);
    float* bnpart = (float*)p; p += align256((size_t)256 * BN_G * 4);
    unsigned short* Wt1 = (unsigned short*)p; p += align256(128 * 128 * 2);
    unsigned short* Wt2 = (unsigned short*)p; p += align256(128 * 384 * 2);
    unsigned short* Wtc = (unsigned short*)p; p += align256(128 * 256 * 2);
    unsigned short* xb16 = (unsigned short*)p; p += align256((size_t)N * 128 * 2);
    unsigned short* n16  = (unsigned short*)p; p += align256((size_t)N * 128 * 2);  // noise, then hs3
    unsigned short* h16  = (unsigned short*)p; p += align256((size_t)N * 128 * 2);  // h1, then h2

    float* colsum   = stats;
    float* colsumsq = stats + 128;
    float* scale    = stats + 256;
    float* shift    = stats + 384;

    float* dout = (float*)d_out;                       // N*128 fp32
    unsigned short* hs12 = (unsigned short*)d_out;     // conv1/2 hs scratch (bf16, fits)
    unsigned short* hs3  = n16;                        // noise dead after conv2
    float* zm = dout;                                  // [N*64]
    float* zs = dout + (size_t)N * 64;                 // [N*64]

    const int gblocks = (N + 63) / 64;
    const int nblocks4 = (N + 3) / 4;

    // --- graph structure + BN stats + conversions ---
    zero_i32<<<(N + 255) / 256, 256, 0, stream>>>(cnt, N);
    count_deg<<<(E + 255) / 256, 256, 0, stream>>>(ei, cnt, E);
    bn_stats<<<BN_G, 256, 0, stream>>>((const float4*)x, bnpart, N);
    bn_reduce<<<256, 256, 0, stream>>>((const float4*)bnpart, stats);
    bn_finalize<<<1, 128, 0, stream>>>(colsum, colsumsq, gamma, beta, scale, shift, 1.0f / (float)N);
    scan_blocks<<<nb, SCAN_BLK, 0, stream>>>(cnt, row_ptr, bsums, N);
    scan_bsums<<<1, 64, 0, stream>>>(bsums, nb);
    scan_add<<<(N + 255) / 256, 256, 0, stream>>>(row_ptr, bsums, N, E);
    dinv_from_cnt<<<(N + 255) / 256, 256, 0, stream>>>(cnt, dinv, N);
    fill_edges<<<(E + 255) / 256, 256, 0, stream>>>(ei, row_ptr, cnt, edge_src, E);
    convert_inputs<<<(N * 32 + 255) / 256, 256, 0, stream>>>(
        (const float4*)x, (const float4*)noise, scale, shift,
        (ushort4*)xb16, (ushort4*)n16, N * 32);
    transpose_w<<<(128 * 128 + 255) / 256, 256, 0, stream>>>(W1, Wt1, 128, 128);
    transpose_w<<<(384 * 128 + 255) / 256, 256, 0, stream>>>(W2, Wt2, 384, 128);
    transpose_w<<<(256 * 64 + 255) / 256, 256, 0, stream>>>(Wm, Wtc, 256, 64);
    transpose_w<<<(256 * 64 + 255) / 256, 256, 0, stream>>>(Ws, Wtc + 64 * 256, 256, 64);

    // conv1
    gemm_mfma<1><<<gblocks, 256, 0, stream>>>(xb16, nullptr, nullptr, Wt1, dinv, hs12, N);
    gather16<true><<<nblocks4, 256, 0, stream>>>((const uint4*)hs12, dinv, row_ptr,
                                                 edge_src, b1, (uint4*)h16, N);
    // conv2
    gemm_mfma<3><<<gblocks, 256, 0, stream>>>(xb16, n16, h16, Wt2, dinv, hs12, N);
    gather16<true><<<nblocks4, 256, 0, stream>>>((const uint4*)hs12, dinv, row_ptr,
                                                 edge_src, b2, (uint4*)h16, N);
    // mean/logstd fused (hs -> n16 slot; d_out now gets final fp32 outputs)
    gemm_mfma<2><<<gblocks, 256, 0, stream>>>(xb16, h16, nullptr, Wtc, dinv, hs3, N);
    gather_dual<<<nblocks4, 256, 0, stream>>>((const uint4*)hs3, dinv, row_ptr,
                                              edge_src, bm, bs, zm, zs, N);
}